// Round 3
// baseline (2097.320 us; speedup 1.0000x reference)
//
#include <hip/hip_runtime.h>
#include <hip/hip_bf16.h>
#include <math.h>

typedef __bf16 bf16;
typedef __attribute__((ext_vector_type(8))) __bf16 v8bf;
typedef __attribute__((ext_vector_type(4))) float v4f;
typedef _Float16 f16;
typedef __attribute__((ext_vector_type(8))) _Float16 v8h;
typedef __attribute__((ext_vector_type(4))) _Float16 v4h;

// XCD-ownership block swizzle (128 tiles). Requires gridDim.y % 8 == 0.
__device__ __forceinline__ void xcd_swizzle(int& bm, int& bn) {
  const int nx = gridDim.x;
  const int id = blockIdx.y * nx + blockIdx.x;
  const int slot = id >> 3;
  const int row_in = slot / nx;
  const int bmi = (id & 7) * (gridDim.y >> 3) + row_in;
  const int bni = slot - row_in * nx;
  bm = bmi << 7; bn = bni << 7;
}

// same, 256x256 tiles
__device__ __forceinline__ void xcd_swizzle256(int& bm, int& bn) {
  const int nx = gridDim.x;
  const int id = blockIdx.y * nx + blockIdx.x;
  const int slot = id >> 3;
  const int row_in = slot / nx;
  const int bmi = (id & 7) * (gridDim.y >> 3) + row_in;
  const int bni = slot - row_in * nx;
  bm = bmi << 8; bn = bni << 8;
}

// ---------------------------------------------------------------------------
// small prep kernels
// ---------------------------------------------------------------------------
__global__ void wconv_t(const float* __restrict__ W, bf16* __restrict__ Wt, int Kd, int Nd) {
  int e = blockIdx.x * 256 + threadIdx.x;
  if (e < Kd * Nd) {
    int k = e / Nd, n = e - k * Nd;
    Wt[n * Kd + k] = (bf16)W[e];   // store transposed [N][K] for gemm_bt
  }
}

// fp32 -> 2-plane fp16 split, transposed, pre-scaled by 2048
__global__ void wsplit_t(const float* __restrict__ W, f16* __restrict__ W0,
                         f16* __restrict__ W1, int Kd, int Nd) {
  int e = blockIdx.x * 256 + threadIdx.x;
  if (e < Kd * Nd) {
    int k = e / Nd, n = e - k * Nd;
    float v = W[e] * 2048.0f;
    f16 h0 = (f16)v;
    f16 h1 = (f16)(v - (float)h0);
    W0[n * Kd + k] = h0;
    W1[n * Kd + k] = h1;
  }
}

__global__ void cbt_k(const float* __restrict__ cb, float* __restrict__ cbT) {
  int e = blockIdx.x * 256 + threadIdx.x;   // 3*256*64 total
  if (e < 3 * 256 * 64) {
    int l = e >> 14, rem = e & 16383;
    int c = rem >> 6, d = rem & 63;
    cbT[l * 16384 + d * 256 + c] = cb[e];   // [l][d][c]
  }
}

__global__ void nhn_k(const float* __restrict__ cb, float* __restrict__ nhn) {
  int l = blockIdx.x, c = threadIdx.x;      // grid 3 x 256
  const float* p = cb + l * 16384 + c * 64;
  double s = 0.0;
  for (int d = 0; d < 64; ++d) { double v = (double)p[d]; s += v * v; }
  nhn[l * 256 + c] = (float)(-0.5 * s);
}

// ---------------------------------------------------------------------------
// fp32 GEMM, 128x128 tile, BK=32, 8x8 per thread.
// EPI: 0 = SiLU->f32, 1 = +bias->f32, 2 = +bias, LN(128), ReLU -> f32 (needs gridDim.x==1,N==128)
// ---------------------------------------------------------------------------
template <int EPI>
__global__ __launch_bounds__(256, 2) void sgemm128(
    const float* __restrict__ A, const float* __restrict__ W,
    const float* __restrict__ bias, const float* __restrict__ lng,
    const float* __restrict__ lnb, float* __restrict__ C, int N, int Kd) {
  __shared__ float As[32][132];   // [k][m], padded
  __shared__ float Bs[32][128];   // [k][n]
  const int tid = threadIdx.x;
  const int w = tid >> 6, l = tid & 63;
  int tx, ty;
  if (EPI == 2) { tx = tid & 15; ty = tid >> 4; }
  else { tx = ((w & 1) << 3) | (l & 7); ty = ((w >> 1) << 3) | (l >> 3); }
  int bm, bn;
  xcd_swizzle(bm, bn);

  float acc[8][8];
#pragma unroll
  for (int i = 0; i < 8; ++i)
#pragma unroll
    for (int j = 0; j < 8; ++j) acc[i][j] = 0.0f;

  for (int k0 = 0; k0 < Kd; k0 += 32) {
    __syncthreads();
#pragma unroll
    for (int jj = 0; jj < 4; ++jj) {
      int p = tid + 256 * jj;
      int arow = p >> 3, aks = (p & 7) << 2;
      float4 v = *(const float4*)(A + (size_t)(bm + arow) * Kd + k0 + aks);
      As[aks][arow] = v.x; As[aks + 1][arow] = v.y;
      As[aks + 2][arow] = v.z; As[aks + 3][arow] = v.w;
      int bk = p >> 5, bns = (p & 31) << 2;
      float4 u = *(const float4*)(W + (size_t)(k0 + bk) * N + bn + bns);
      *(float4*)(&Bs[bk][bns]) = u;
    }
    __syncthreads();
    float cacc[8][8];
#pragma unroll
    for (int i = 0; i < 8; ++i)
#pragma unroll
      for (int j = 0; j < 8; ++j) cacc[i][j] = 0.0f;
#pragma unroll 4
    for (int kk = 0; kk < 32; ++kk) {
      float a[8], b[8];
#pragma unroll
      for (int i = 0; i < 8; ++i) a[i] = As[kk][ty * 8 + i];
#pragma unroll
      for (int j = 0; j < 8; ++j) b[j] = Bs[kk][tx * 8 + j];
#pragma unroll
      for (int i = 0; i < 8; ++i)
#pragma unroll
        for (int j = 0; j < 8; ++j) cacc[i][j] = fmaf(a[i], b[j], cacc[i][j]);
    }
#pragma unroll
    for (int i = 0; i < 8; ++i)
#pragma unroll
      for (int j = 0; j < 8; ++j) acc[i][j] += cacc[i][j];
  }

  const int colb = bn + tx * 8;
  if (EPI == 0) {
#pragma unroll
    for (int i = 0; i < 8; ++i) {
      int row = bm + ty * 8 + i;
      float o[8];
#pragma unroll
      for (int j = 0; j < 8; ++j) { float v = acc[i][j]; o[j] = v / (1.0f + expf(-v)); }
      *(float4*)(C + (size_t)row * N + colb) = make_float4(o[0], o[1], o[2], o[3]);
      *(float4*)(C + (size_t)row * N + colb + 4) = make_float4(o[4], o[5], o[6], o[7]);
    }
  } else if (EPI == 1) {
    float bb[8];
#pragma unroll
    for (int j = 0; j < 8; ++j) bb[j] = bias[colb + j];
#pragma unroll
    for (int i = 0; i < 8; ++i) {
      int row = bm + ty * 8 + i;
      float o[8];
#pragma unroll
      for (int j = 0; j < 8; ++j) o[j] = acc[i][j] + bb[j];
      *(float4*)(C + (size_t)row * N + colb) = make_float4(o[0], o[1], o[2], o[3]);
      *(float4*)(C + (size_t)row * N + colb + 4) = make_float4(o[4], o[5], o[6], o[7]);
    }
  } else {
    float bb[8], lg[8], lb[8];
#pragma unroll
    for (int j = 0; j < 8; ++j) { bb[j] = bias[colb + j]; lg[j] = lng[colb + j]; lb[j] = lnb[colb + j]; }
#pragma unroll
    for (int i = 0; i < 8; ++i) {
      int row = bm + ty * 8 + i;
      float v[8]; float s = 0.0f;
#pragma unroll
      for (int j = 0; j < 8; ++j) { v[j] = acc[i][j] + bb[j]; s += v[j]; }
      s += __shfl_xor(s, 1); s += __shfl_xor(s, 2); s += __shfl_xor(s, 4); s += __shfl_xor(s, 8);
      float mean = s * (1.0f / 128.0f);
      float ss = 0.0f;
#pragma unroll
      for (int j = 0; j < 8; ++j) { float t = v[j] - mean; ss += t * t; }
      ss += __shfl_xor(ss, 1); ss += __shfl_xor(ss, 2); ss += __shfl_xor(ss, 4); ss += __shfl_xor(ss, 8);
      float rs = 1.0f / sqrtf(ss * (1.0f / 128.0f) + 1e-5f);
      float o[8];
#pragma unroll
      for (int j = 0; j < 8; ++j) o[j] = fmaxf((v[j] - mean) * rs * lg[j] + lb[j], 0.0f);
      *(float4*)(C + (size_t)row * N + colb) = make_float4(o[0], o[1], o[2], o[3]);
      *(float4*)(C + (size_t)row * N + colb + 4) = make_float4(o[4], o[5], o[6], o[7]);
    }
  }
}

// ---------------------------------------------------------------------------
// fp32 GEMM, 128x64 tile (N fixed 64), BK=32, 8x4 per thread.
// EPI: 0 = l2norm row -> C, 1 = +bias -> C, 2 = gate (sigmoid->C, gate*aux->C2)
// ---------------------------------------------------------------------------
template <int EPI>
__global__ __launch_bounds__(256, 2) void sgemm64(
    const float* __restrict__ A, const float* __restrict__ W,
    const float* __restrict__ bias, const float* __restrict__ aux,
    float* __restrict__ C, float* __restrict__ C2, int Kd) {
  __shared__ float As[32][132];
  __shared__ float Bs[32][64];
  const int tid = threadIdx.x;
  const int tx = tid & 15, ty = tid >> 4;
  const int bm = blockIdx.x << 7;

  float acc[8][4];
#pragma unroll
  for (int i = 0; i < 8; ++i)
#pragma unroll
    for (int j = 0; j < 4; ++j) acc[i][j] = 0.0f;

  for (int k0 = 0; k0 < Kd; k0 += 32) {
    __syncthreads();
#pragma unroll
    for (int jj = 0; jj < 4; ++jj) {
      int p = tid + 256 * jj;
      int arow = p >> 3, aks = (p & 7) << 2;
      float4 v = *(const float4*)(A + (size_t)(bm + arow) * Kd + k0 + aks);
      As[aks][arow] = v.x; As[aks + 1][arow] = v.y;
      As[aks + 2][arow] = v.z; As[aks + 3][arow] = v.w;
    }
#pragma unroll
    for (int jj = 0; jj < 2; ++jj) {
      int p = tid + 256 * jj;
      int bk = p >> 4, bns = (p & 15) << 2;
      float4 u = *(const float4*)(W + (size_t)(k0 + bk) * 64 + bns);
      *(float4*)(&Bs[bk][bns]) = u;
    }
    __syncthreads();
    float cacc[8][4];
#pragma unroll
    for (int i = 0; i < 8; ++i)
#pragma unroll
      for (int j = 0; j < 4; ++j) cacc[i][j] = 0.0f;
#pragma unroll 4
    for (int kk = 0; kk < 32; ++kk) {
      float a[8], b[4];
#pragma unroll
      for (int i = 0; i < 8; ++i) a[i] = As[kk][ty * 8 + i];
#pragma unroll
      for (int j = 0; j < 4; ++j) b[j] = Bs[kk][tx * 4 + j];
#pragma unroll
      for (int i = 0; i < 8; ++i)
#pragma unroll
        for (int j = 0; j < 4; ++j) cacc[i][j] = fmaf(a[i], b[j], cacc[i][j]);
    }
#pragma unroll
    for (int i = 0; i < 8; ++i)
#pragma unroll
      for (int j = 0; j < 4; ++j) acc[i][j] += cacc[i][j];
  }

  const int colb = tx * 4;
  if (EPI == 0) {           // l2norm(z) -> rn
#pragma unroll
    for (int i = 0; i < 8; ++i) {
      int row = bm + ty * 8 + i;
      float ss = 0.0f;
#pragma unroll
      for (int j = 0; j < 4; ++j) ss += acc[i][j] * acc[i][j];
      ss += __shfl_xor(ss, 1); ss += __shfl_xor(ss, 2); ss += __shfl_xor(ss, 4); ss += __shfl_xor(ss, 8);
      float nrm = fmaxf(sqrtf(ss), 1e-12f);
      *(float4*)(C + (size_t)row * 64 + colb) =
          make_float4(acc[i][0] / nrm, acc[i][1] / nrm, acc[i][2] / nrm, acc[i][3] / nrm);
    }
  } else if (EPI == 1) {
    float bb[4];
#pragma unroll
    for (int j = 0; j < 4; ++j) bb[j] = bias[colb + j];
#pragma unroll
    for (int i = 0; i < 8; ++i) {
      int row = bm + ty * 8 + i;
      *(float4*)(C + (size_t)row * 64 + colb) =
          make_float4(acc[i][0] + bb[0], acc[i][1] + bb[1], acc[i][2] + bb[2], acc[i][3] + bb[3]);
    }
  } else {                  // gate: sigmoid -> C (gate_values), gate*collab -> C2 (denoised)
    float bb[4];
#pragma unroll
    for (int j = 0; j < 4; ++j) bb[j] = bias[colb + j];
#pragma unroll
    for (int i = 0; i < 8; ++i) {
      int row = bm + ty * 8 + i;
      float4 av = *(const float4*)(aux + (size_t)row * 64 + colb);
      float g[4];
#pragma unroll
      for (int j = 0; j < 4; ++j) g[j] = 1.0f / (1.0f + expf(-(acc[i][j] + bb[j])));
      *(float4*)(C + (size_t)row * 64 + colb) = make_float4(g[0], g[1], g[2], g[3]);
      *(float4*)(C2 + (size_t)row * 64 + colb) =
          make_float4(g[0] * av.x, g[1] * av.y, g[2] * av.z, g[3] * av.w);
    }
  }
}

// ---------------------------------------------------------------------------
// fusion layernorm over 832; wave per row. Emits the 2-plane f16 split of the
// normalized row (x256 scale) so the encoder GEMM consumes pure f16 planes.
// Split values are bitwise identical to the old per-tile split of the fp32 y.
// ---------------------------------------------------------------------------
__global__ __launch_bounds__(256) void fuse_ln(
    const float* __restrict__ sem, const float* __restrict__ den,
    const float* __restrict__ fg, const float* __restrict__ fb,
    f16* __restrict__ fA0, f16* __restrict__ fA1) {
  const int w = threadIdx.x >> 6, l = threadIdx.x & 63;
  float fgv[13], fbv[13];
#pragma unroll
  for (int q = 0; q < 12; ++q) { fgv[q] = fg[q * 64 + l]; fbv[q] = fb[q * 64 + l]; }
  fgv[12] = fg[768 + l]; fbv[12] = fb[768 + l];
  for (int it = 0; it < 4; ++it) {
    int r = (blockIdx.x * 4 + w) * 4 + it;
    float sv[12];
#pragma unroll
    for (int q = 0; q < 12; ++q) sv[q] = sem[(size_t)r * 768 + q * 64 + l];
    float dv = den[(size_t)r * 64 + l];
    float s = dv;
#pragma unroll
    for (int q = 0; q < 12; ++q) s += sv[q];
#pragma unroll
    for (int m = 1; m < 64; m <<= 1) s += __shfl_xor(s, m, 64);
    float mean = s * (1.0f / 832.0f);
    float t0 = dv - mean;
    float ss = t0 * t0;
#pragma unroll
    for (int q = 0; q < 12; ++q) { float t = sv[q] - mean; ss += t * t; }
#pragma unroll
    for (int m = 1; m < 64; m <<= 1) ss += __shfl_xor(ss, m, 64);
    float sc = 1.0f / sqrtf(ss * (1.0f / 832.0f) + 1e-5f);
#pragma unroll
    for (int q = 0; q < 13; ++q) {
      float y = (q < 12) ? ((sv[q] - mean) * sc * fgv[q] + fbv[q])
                         : (t0 * sc * fgv[12] + fbv[12]);
      float t = y * 256.0f;
      f16 h0 = (f16)t;
      size_t idx = (size_t)r * 832 + q * 64 + l;
      fA0[idx] = h0;
      fA1[idx] = (f16)(t - (float)h0);
    }
  }
}

// ---------------------------------------------------------------------------
// RQ argmax + update; wave per row, 16 rows/wave
// ---------------------------------------------------------------------------
template <int LAYER>
__global__ __launch_bounds__(256) void argupd(
    const float* __restrict__ scores, const float* __restrict__ cbl,
    float* __restrict__ rn, float* __restrict__ zq, float* __restrict__ codes,
    float* __restrict__ loss, bf16* __restrict__ zqb) {
  const int w = threadIdx.x >> 6, l = threadIdx.x & 63;
  const int base = (blockIdx.x * 4 + w) * 16;
  float lacc = 0.0f;
  for (int it = 0; it < 16; ++it) {
    int r = base + it;
    float4 s4 = *(const float4*)(scores + (size_t)r * 256 + l * 4);
    float bs = s4.x; int bi = l * 4;
    if (s4.y > bs) { bs = s4.y; bi = l * 4 + 1; }
    if (s4.z > bs) { bs = s4.z; bi = l * 4 + 2; }
    if (s4.w > bs) { bs = s4.w; bi = l * 4 + 3; }
#pragma unroll
    for (int m = 1; m < 64; m <<= 1) {
      float os = __shfl_xor(bs, m, 64);
      int oi = __shfl_xor(bi, m, 64);
      if (os > bs || (os == bs && oi < bi)) { bs = os; bi = oi; }
    }
    float e = cbl[bi * 64 + l];
    float rl = rn[(size_t)r * 64 + l];
    float emr = e - rl;
    float zql = rl + emr;          // straight-through forward value, ref rounding order
    lacc += emr * emr;
    if (l == 0) codes[r * 3 + LAYER] = (float)bi;
    if (LAYER == 0) {
      zq[(size_t)r * 64 + l] = zql;
    } else if (LAYER == 1) {
      zq[(size_t)r * 64 + l] += zql;
    } else {
      float tot = zq[(size_t)r * 64 + l] + zql;
      zq[(size_t)r * 64 + l] = tot;
      zqb[(size_t)r * 64 + l] = (bf16)tot;
    }
    if (LAYER < 2) {
      float rnew = rl - zql;
      float ss = rnew * rnew;
#pragma unroll
      for (int m = 1; m < 64; m <<= 1) ss += __shfl_xor(ss, m, 64);
      float nrm = fmaxf(sqrtf(ss), 1e-12f);
      rn[(size_t)r * 64 + l] = rnew / nrm;
    }
  }
#pragma unroll
  for (int m = 1; m < 64; m <<= 1) lacc += __shfl_xor(lacc, m, 64);
  if (l == 0) {
    float v = lacc * (1.0f / 4194304.0f);   // 1/(65536*64), exact pow2
    atomicAdd(loss, v);
    atomicAdd(loss + 1, v);
  }
}

// ---------------------------------------------------------------------------
// async global->LDS helper
// ---------------------------------------------------------------------------
typedef __attribute__((address_space(3))) void lds_void_t;
typedef __attribute__((address_space(1))) const void gbl_void_t;
__device__ __forceinline__ void gl_lds16(const void* g, void* l) {
  __builtin_amdgcn_global_load_lds((gbl_void_t*)g, (lds_void_t*)l, 16, 0, 0);
}

// ---------------------------------------------------------------------------
// bf16 MFMA GEMM (m97 structure): 128x128 tile, BK=32 (kept for N=128 case)
// EPI: 0 = SiLU->bf16, 1 = +bias->bf16, 2 = +bias->f32
// ---------------------------------------------------------------------------
template <int EPI>
__global__ __launch_bounds__(256, 3) void bgemm(
    const bf16* __restrict__ A, const bf16* __restrict__ Wt,
    const float* __restrict__ bias, void* __restrict__ Cv, int N, int Kd) {
  __shared__ __align__(16) bf16 As[128 * 32];
  __shared__ __align__(16) bf16 Bs[128 * 32];
  const int tid = threadIdx.x;
  const int w = tid >> 6, l = tid & 63;
  int bm, bn;
  xcd_swizzle(bm, bn);
  const int wm = (w >> 1) << 6, wn = (w & 1) << 6;

  v4f acc[4][4];
  v4f z4 = {0.0f, 0.0f, 0.0f, 0.0f};
#pragma unroll
  for (int i = 0; i < 4; ++i)
#pragma unroll
    for (int j = 0; j < 4; ++j) acc[i][j] = z4;

  const int srow = (w << 5) + (l >> 2);
  const int skc = (l & 3) << 3;
  const bf16* ga0 = A + (size_t)(bm + srow) * Kd + skc;
  const bf16* gb0 = Wt + (size_t)(bn + srow) * Kd + skc;
  char* la0 = (char*)As + (w << 11);
  char* lb0 = (char*)Bs + (w << 11);

  for (int k0 = 0; k0 < Kd; k0 += 32) {
    __syncthreads();
    gl_lds16(ga0 + k0, la0);
    gl_lds16(ga0 + (size_t)16 * Kd + k0, la0 + 1024);
    gl_lds16(gb0 + k0, lb0);
    gl_lds16(gb0 + (size_t)16 * Kd + k0, lb0 + 1024);
    __syncthreads();
    v8bf af[4], bfr[4];
#pragma unroll
    for (int f = 0; f < 4; ++f) {
      af[f] = *(const v8bf*)(As + (wm + f * 16 + (l & 15)) * 32 + ((l >> 4) << 3));
      bfr[f] = *(const v8bf*)(Bs + (wn + f * 16 + (l & 15)) * 32 + ((l >> 4) << 3));
    }
#pragma unroll
    for (int mf = 0; mf < 4; ++mf)
#pragma unroll
      for (int nf = 0; nf < 4; ++nf)
        acc[mf][nf] = __builtin_amdgcn_mfma_f32_16x16x32_bf16(af[mf], bfr[nf], acc[mf][nf], 0, 0, 0);
  }

  const int cbase = bn + wn + (l & 15);
  float bb[4];
  if (EPI != 0) {
#pragma unroll
    for (int nf = 0; nf < 4; ++nf) bb[nf] = bias[cbase + nf * 16];
  }
#pragma unroll
  for (int mf = 0; mf < 4; ++mf) {
#pragma unroll
    for (int i = 0; i < 4; ++i) {
      int row = bm + wm + mf * 16 + ((l >> 4) << 2) + i;
#pragma unroll
      for (int nf = 0; nf < 4; ++nf) {
        int col = cbase + nf * 16;
        float v = acc[mf][nf][i];
        if (EPI == 0) {
          v = v / (1.0f + __expf(-v));
          ((bf16*)Cv)[(size_t)row * N + col] = (bf16)v;
        } else if (EPI == 1) {
          v += bb[nf];
          ((bf16*)Cv)[(size_t)row * N + col] = (bf16)v;
        } else {
          v += bb[nf];
          ((float*)Cv)[(size_t)row * N + col] = v;
        }
      }
    }
  }
}

// ---------------------------------------------------------------------------
// f16 2-plane GEMM, 128x128 tile, BK=32, m97 structure (layer-3, N=128).
// Same as bgemm but 4 plane buffers + 3-product MFMA; SiLU -> fp32.
// ---------------------------------------------------------------------------
__global__ __launch_bounds__(256, 3) void hgemm_p(
    const f16* __restrict__ A0, const f16* __restrict__ A1,
    const f16* __restrict__ W0, const f16* __restrict__ W1,
    float* __restrict__ C, int N, int Kd) {
  __shared__ __align__(16) f16 As0[128 * 32];
  __shared__ __align__(16) f16 As1[128 * 32];
  __shared__ __align__(16) f16 Bs0[128 * 32];
  __shared__ __align__(16) f16 Bs1[128 * 32];
  const int tid = threadIdx.x;
  const int w = tid >> 6, l = tid & 63;
  int bm, bn;
  xcd_swizzle(bm, bn);
  const int wm = (w >> 1) << 6, wn = (w & 1) << 6;

  v4f acc[4][4];
  v4f z4 = {0.0f, 0.0f, 0.0f, 0.0f};
#pragma unroll
  for (int i = 0; i < 4; ++i)
#pragma unroll
    for (int j = 0; j < 4; ++j) acc[i][j] = z4;

  const int srow = (w << 5) + (l >> 2);
  const int skc = (l & 3) << 3;
  const f16* ga0 = A0 + (size_t)(bm + srow) * Kd + skc;
  const f16* ga1 = A1 + (size_t)(bm + srow) * Kd + skc;
  const f16* gb0 = W0 + (size_t)(bn + srow) * Kd + skc;
  const f16* gb1 = W1 + (size_t)(bn + srow) * Kd + skc;
  char* la0 = (char*)As0 + (w << 11);
  char* la1 = (char*)As1 + (w << 11);
  char* lb0 = (char*)Bs0 + (w << 11);
  char* lb1 = (char*)Bs1 + (w << 11);

  for (int k0 = 0; k0 < Kd; k0 += 32) {
    __syncthreads();
    gl_lds16(ga0 + k0, la0);
    gl_lds16(ga0 + (size_t)16 * Kd + k0, la0 + 1024);
    gl_lds16(ga1 + k0, la1);
    gl_lds16(ga1 + (size_t)16 * Kd + k0, la1 + 1024);
    gl_lds16(gb0 + k0, lb0);
    gl_lds16(gb0 + (size_t)16 * Kd + k0, lb0 + 1024);
    gl_lds16(gb1 + k0, lb1);
    gl_lds16(gb1 + (size_t)16 * Kd + k0, lb1 + 1024);
    __syncthreads();
    v8h a0f[4], a1f[4], b0f[4], b1f[4];
#pragma unroll
    for (int f = 0; f < 4; ++f) {
      int ro = (wm + f * 16 + (l & 15)) * 32 + ((l >> 4) << 3);
      int co = (wn + f * 16 + (l & 15)) * 32 + ((l >> 4) << 3);
      a0f[f] = *(const v8h*)(As0 + ro);
      a1f[f] = *(const v8h*)(As1 + ro);
      b0f[f] = *(const v8h*)(Bs0 + co);
      b1f[f] = *(const v8h*)(Bs1 + co);
    }
#pragma unroll
    for (int mf = 0; mf < 4; ++mf)
#pragma unroll
      for (int nf = 0; nf < 4; ++nf) {
        acc[mf][nf] = __builtin_amdgcn_mfma_f32_16x16x32_f16(a0f[mf], b1f[nf], acc[mf][nf], 0, 0, 0);
        acc[mf][nf] = __builtin_amdgcn_mfma_f32_16x16x32_f16(a1f[mf], b0f[nf], acc[mf][nf], 0, 0, 0);
        acc[mf][nf] = __builtin_amdgcn_mfma_f32_16x16x32_f16(a0f[mf], b0f[nf], acc[mf][nf], 0, 0, 0);
      }
  }

  const float sc = 1.0f / (256.0f * 2048.0f);   // 2^-19 exact
  const int cbase = bn + wn + (l & 15);
#pragma unroll
  for (int mf = 0; mf < 4; ++mf) {
#pragma unroll
    for (int i = 0; i < 4; ++i) {
      int row = bm + wm + mf * 16 + ((l >> 4) << 2) + i;
#pragma unroll
      for (int nf = 0; nf < 4; ++nf) {
        int col = cbase + nf * 16;
        float v = acc[mf][nf][i] * sc;
        v = v / (1.0f + expf(-v));              // SiLU, precision path
        C[(size_t)row * N + col] = v;
      }
    }
  }
}

// ---------------------------------------------------------------------------
// bf16 MFMA GEMM, 256x256 tile, BK=64, 8 waves, 8-phase counted-vmcnt schedule
// (verified round 2). See round-2 comments for the schedule/vmcnt proof.
// ---------------------------------------------------------------------------
__device__ __forceinline__ void stage_half(const bf16* __restrict__ src, int Kd,
                                           int rbase, int k0, char* hb8,
                                           int wid, int l) {
#pragma unroll
  for (int j = 0; j < 2; ++j) {
    int Cc = wid * 128 + j * 64 + l;
    int cc = Cc ^ (((Cc >> 3) & 3) << 1);
    gl_lds16(src + (size_t)(rbase + (cc >> 3)) * Kd + k0 + (cc & 7) * 8,
             hb8 + wid * 2048 + j * 1024);
  }
}

__device__ __forceinline__ v8bf ldsfrag(const char* base, int row, int kb) {
  int p = row * 128 + kb;
  p ^= ((p >> 7) & 3) << 5;
  return *(const v8bf*)(base + p);
}

__device__ __forceinline__ void rd_a(v8bf (&af)[2][4], const char* ab, int mh, int l) {
  const int rb = mh * 64 + (l & 15);
  const int kb = (l >> 4) * 16;
#pragma unroll
  for (int ks = 0; ks < 2; ++ks)
#pragma unroll
    for (int mf = 0; mf < 4; ++mf)
      af[ks][mf] = ldsfrag(ab, rb + mf * 16, ks * 64 + kb);
}

__device__ __forceinline__ void rd_b(v8bf (&bfr)[2][2], const char* bbp, int nh, int wl, int l) {
  const int rb = wl + nh * 32 + (l & 15);
  const int kb = (l >> 4) * 16;
#pragma unroll
  for (int ks = 0; ks < 2; ++ks)
#pragma unroll
    for (int nf = 0; nf < 2; ++nf)
      bfr[ks][nf] = ldsfrag(bbp, rb + nf * 16, ks * 64 + kb);
}

__device__ __forceinline__ void qmfma(v4f (&q)[4][2], const v8bf (&af)[2][4],
                                      const v8bf (&bfr)[2][2]) {
  __builtin_amdgcn_s_setprio(1);
#pragma unroll
  for (int ks = 0; ks < 2; ++ks)
#pragma unroll
    for (int mf = 0; mf < 4; ++mf)
#pragma unroll
      for (int nf = 0; nf < 2; ++nf)
        q[mf][nf] = __builtin_amdgcn_mfma_f32_16x16x32_bf16(af[ks][mf], bfr[ks][nf],
                                                            q[mf][nf], 0, 0, 0);
  __builtin_amdgcn_s_setprio(0);
}

#define PHASE_BAR() do { __builtin_amdgcn_s_barrier(); __builtin_amdgcn_sched_barrier(0); } while (0)

template <int EPI>
__global__ __launch_bounds__(512, 2) void bgemm8(
    const bf16* __restrict__ A, const bf16* __restrict__ Wt,
    const float* __restrict__ bias, void* __restrict__ Cv, int N, int Kd) {
  __shared__ __align__(16) char smem[131072];
  const int tid = threadIdx.x;
  const int wid = tid >> 6, l = tid & 63;
  int bm, bn;
  xcd_swizzle256(bm, bn);
  const int ha = wid >> 2;            // this wave's A half
  const int hbv = (wid & 3) >> 1;     // this wave's B half
  const int wl = (wid & 1) * 64;      // B row base within half
  const int NT = Kd >> 6;             // K-tiles (BK=64), NT >= 2

  v4f acc[2][2][4][2];
  v4f z4 = {0.0f, 0.0f, 0.0f, 0.0f};
#pragma unroll
  for (int a = 0; a < 2; ++a)
#pragma unroll
    for (int b = 0; b < 2; ++b)
#pragma unroll
      for (int c = 0; c < 4; ++c)
#pragma unroll
        for (int d = 0; d < 2; ++d) acc[a][b][c][d] = z4;

  // prologue: tile0 {A0,A1,B0,B1}, tile1 {A0,A1}; keep 4 in flight (=A(1))
  stage_half(A,  Kd, bm,       0,  smem + 0,     wid, l);
  stage_half(A,  Kd, bm + 128, 0,  smem + 16384, wid, l);
  stage_half(Wt, Kd, bn,       0,  smem + 32768, wid, l);
  stage_half(Wt, Kd, bn + 128, 0,  smem + 49152, wid, l);
  stage_half(A,  Kd, bm,       64, smem + 65536, wid, l);
  stage_half(A,  Kd, bm + 128, 64, smem + 81920, wid, l);
  asm volatile("s_waitcnt vmcnt(4)" ::: "memory");
  PHASE_BAR();

  for (int K = 0; K < NT; ++K) {
    const int cur = K & 1;
    const char* ab = smem + cur * 65536 + ha * 16384;
    const char* bb = smem + cur * 65536 + 32768 + hbv * 16384;
    char* stB = smem + ((K + 1) & 1) * 65536 + 32768;
    char* stA = smem + cur * 65536;
    const int kB = (K + 1 < NT) ? (K + 1) << 6 : 0;   // clamp: dummy keeps vmcnt exact
    const int kA = (K + 2 < NT) ? (K + 2) << 6 : 0;
    v8bf a0[2][4], a1[2][4], b0[2][2], b1[2][2];

    // q0: Q(0,0) — read a0,b0; stage B-half0(K+1)
    rd_a(a0, ab, 0, l);
    rd_b(b0, bb, 0, wl, l);
    stage_half(Wt, Kd, bn, kB, stB, wid, l);
    PHASE_BAR();
    qmfma(acc[0][0], a0, b0);
    PHASE_BAR();
    // q1: Q(0,1) — read b1; stage B-half1(K+1); a0 dies here
    rd_b(b1, bb, 1, wl, l);
    stage_half(Wt, Kd, bn + 128, kB, stB + 16384, wid, l);
    PHASE_BAR();
    qmfma(acc[0][1], a0, b1);
    PHASE_BAR();
    // q2: Q(1,0) — read a1 (last A read of this tile); b0 dies here
    rd_a(a1, ab, 1, l);
    PHASE_BAR();
    qmfma(acc[1][0], a1, b0);
    PHASE_BAR();
    // q3: Q(1,1) — reg-only compute; stage A(K+2) over this tile's A region
    stage_half(A, Kd, bm, kA, stA, wid, l);
    stage_half(A, Kd, bm + 128, kA, stA + 16384, wid, l);
    PHASE_BAR();
    qmfma(acc[1][1], a1, b1);
    asm volatile("s_waitcnt vmcnt(4)" ::: "memory");
    PHASE_BAR();
  }
  asm volatile("s_waitcnt vmcnt(0)" ::: "memory");

  const int r0 = bm + ha * 128 + ((l >> 4) << 2);
  const int c0 = bn + (wid & 3) * 64 + (l & 15);
  float bb4[2][2];
  if (EPI != 0) {
#pragma unroll
    for (int nh = 0; nh < 2; ++nh)
#pragma unroll
      for (int nf = 0; nf < 2; ++nf) bb4[nh][nf] = bias[c0 + nh * 32 + nf * 16];
  }
#pragma unroll
  for (int mh = 0; mh < 2; ++mh)
#pragma unroll
    for (int mf = 0; mf < 4; ++mf)
#pragma unroll
      for (int i = 0; i < 4; ++i) {
        const int row = r0 + mh * 64 + mf * 16 + i;
#pragma unroll
        for (int nh = 0; nh < 2; ++nh)
#pragma unroll
          for (int nf = 0; nf < 2; ++nf) {
            const int col = c0 + nh * 32 + nf * 16;
            float v = acc[mh][nh][mf][nf][i];
            if (EPI == 0) {
              v = v / (1.0f + __expf(-v));
              ((bf16*)Cv)[(size_t)row * N + col] = (bf16)v;
            } else if (EPI == 1) {
              v += bb4[nh][nf];
              ((bf16*)Cv)[(size_t)row * N + col] = (bf16)v;
            } else {
              v += bb4[nh][nf];
              ((float*)Cv)[(size_t)row * N + col] = v;
            }
          }
      }
}

// ---------------------------------------------------------------------------
// f16 2-plane MFMA GEMM, 256x256 tile, BK=32, 8 waves, 8-phase counted-vmcnt
// schedule — the bgemm8 skeleton with {A-half0,A-half1,B-half0,B-half1}
// replaced by {A-plane0,A-plane1,B-plane0,B-plane1} (each 256 rows x 32
// halves = 16 KB; 2 bufs x 4 planes = 128 KiB). 3-product MFMA per fragment
// pair (a0*b1 + a1*b0 + a0*b0, same order as the old hgemm3 -> bitwise-equal
// accumulation). Stage counts/vmcnt identical to bgemm8 (8 loads/iter,
// vmcnt(4) keeps A(K+2)).
// Swizzle for 64B rows: byte bits 4-5 ^= row bits 1-2 (p ^= ((p>>7)&3)<<4);
// applied to the pre-swizzled global source chunk (chunk cc = Cc^((Cc>>3)&3))
// and to the ds_read_b128 address. Rows 0-7 then cover all 32 banks; 16-lane
// column reads are 2-way (free) instead of 8-way.
// Epilogue: SiLU then emit the 2-plane f16 split of the result (x256), so the
// next layer consumes planes directly. Split of the same fp32 value as the
// old load-time split -> bitwise identical downstream.
// ---------------------------------------------------------------------------
__device__ __forceinline__ void stage_plane(const f16* __restrict__ src, int Kd,
                                            int rbase, int k0, char* base,
                                            int wid, int l) {
#pragma unroll
  for (int j = 0; j < 2; ++j) {
    int Cc = wid * 128 + j * 64 + l;
    int cc = Cc ^ ((Cc >> 3) & 3);
    gl_lds16(src + (size_t)(rbase + (cc >> 2)) * Kd + k0 + (cc & 3) * 8,
             base + wid * 2048 + j * 1024);
  }
}

__device__ __forceinline__ v8h ldsfragh(const char* base, int row, int kb) {
  int p = row * 64 + kb;
  p ^= ((p >> 7) & 3) << 4;
  return *(const v8h*)(base + p);
}

__device__ __forceinline__ void rd_a3(v8h (&af)[2][4], const char* a0p,
                                      const char* a1p, int rb, int kb) {
#pragma unroll
  for (int mf = 0; mf < 4; ++mf) {
    af[0][mf] = ldsfragh(a0p, rb + mf * 16, kb);
    af[1][mf] = ldsfragh(a1p, rb + mf * 16, kb);
  }
}

__device__ __forceinline__ void rd_b3(v8h (&bf)[2][2], const char* b0p,
                                      const char* b1p, int rb, int kb) {
#pragma unroll
  for (int nf = 0; nf < 2; ++nf) {
    bf[0][nf] = ldsfragh(b0p, rb + nf * 16, kb);
    bf[1][nf] = ldsfragh(b1p, rb + nf * 16, kb);
  }
}

__device__ __forceinline__ void qmfma3(v4f (&q)[4][2], const v8h (&af)[2][4],
                                       const v8h (&bf)[2][2]) {
  __builtin_amdgcn_s_setprio(1);
#pragma unroll
  for (int mf = 0; mf < 4; ++mf)
#pragma unroll
    for (int nf = 0; nf < 2; ++nf) {
      q[mf][nf] = __builtin_amdgcn_mfma_f32_16x16x32_f16(af[0][mf], bf[1][nf], q[mf][nf], 0, 0, 0);
      q[mf][nf] = __builtin_amdgcn_mfma_f32_16x16x32_f16(af[1][mf], bf[0][nf], q[mf][nf], 0, 0, 0);
      q[mf][nf] = __builtin_amdgcn_mfma_f32_16x16x32_f16(af[0][mf], bf[0][nf], q[mf][nf], 0, 0, 0);
    }
  __builtin_amdgcn_s_setprio(0);
}

__global__ __launch_bounds__(512, 2) void hgemm38(
    const f16* __restrict__ A0, const f16* __restrict__ A1,
    const f16* __restrict__ W0, const f16* __restrict__ W1,
    f16* __restrict__ O0, f16* __restrict__ O1, int N, int Kd) {
  __shared__ __align__(16) char smem[131072];
  const int tid = threadIdx.x;
  const int wid = tid >> 6, l = tid & 63;
  int bm, bn;
  xcd_swizzle256(bm, bn);
  const int ha = wid >> 2;            // this wave's A half (rows ha*128..+127)
  const int wc = (wid & 3) * 64;      // this wave's col base within tile
  const int NT = Kd >> 5;             // K-tiles (BK=32), NT >= 2
  const int kb = (l >> 4) * 16;

  v4f acc[2][2][4][2];
  v4f z4 = {0.0f, 0.0f, 0.0f, 0.0f};
#pragma unroll
  for (int a = 0; a < 2; ++a)
#pragma unroll
    for (int b = 0; b < 2; ++b)
#pragma unroll
      for (int c = 0; c < 4; ++c)
#pragma unroll
        for (int d = 0; d < 2; ++d) acc[a][b][c][d] = z4;

  // prologue: tile0 {A0,A1,B0,B1}, tile1 {A0,A1}; keep 4 in flight (=A(1))
  stage_plane(A0, Kd, bm, 0,  smem + 0,     wid, l);
  stage_plane(A1, Kd, bm, 0,  smem + 16384, wid, l);
  stage_plane(W0, Kd, bn, 0,  smem + 32768, wid, l);
  stage_plane(W1, Kd, bn, 0,  smem + 49152, wid, l);
  stage_plane(A0, Kd, bm, 32, smem + 65536, wid, l);
  stage_plane(A1, Kd, bm, 32, smem + 65536 + 16384, wid, l);
  asm volatile("s_waitcnt vmcnt(4)" ::: "memory");
  PHASE_BAR();

  for (int K = 0; K < NT; ++K) {
    const int cur = K & 1;
    const char* a0p = smem + cur * 65536;
    const char* a1p = a0p + 16384;
    const char* b0p = a0p + 32768;
    const char* b1p = a0p + 49152;
    char* st = smem + ((K + 1) & 1) * 65536;   // other buf (B K+1)
    char* sa = smem + cur * 65536;             // cur buf (A K+2)
    const int kB = (K + 1 < NT) ? (K + 1) << 5 : 0;
    const int kA = (K + 2 < NT) ? (K + 2) << 5 : 0;
    v8h a0[2][4], a1[2][4], b0[2][2], b1[2][2];

    // q0: Q(0,0) — read a0(both planes), b0; stage B-plane0(K+1)
    rd_a3(a0, a0p, a1p, ha * 128 + (l & 15), kb);
    rd_b3(b0, b0p, b1p, wc + (l & 15), kb);
    stage_plane(W0, Kd, bn, kB, st + 32768, wid, l);
    PHASE_BAR();
    qmfma3(acc[0][0], a0, b0);
    PHASE_BAR();
    // q1: Q(0,1) — read b1; stage B-plane1(K+1); a0 dies here
    rd_b3(b1, b0p, b1p, wc + 32 + (l & 15), kb);
    stage_plane(W1, Kd, bn, kB, st + 49152, wid, l);
    PHASE_BAR();
    qmfma3(acc[0][1], a0, b1);
    PHASE_BAR();
    // q2: Q(1,0) — read a1 (last A read of this tile); b0 dies here
    rd_a3(a1, a0p, a1p, ha * 128 + 64 + (l & 15), kb);
    PHASE_BAR();
    qmfma3(acc[1][0], a1, b0);
    PHASE_BAR();
    // q3: Q(1,1) — reg-only compute; stage A(K+2) over this tile's A region
    stage_plane(A0, Kd, bm, kA, sa, wid, l);
    stage_plane(A1, Kd, bm, kA, sa + 16384, wid, l);
    PHASE_BAR();
    qmfma3(acc[1][1], a1, b1);
    asm volatile("s_waitcnt vmcnt(4)" ::: "memory");
    PHASE_BAR();
  }
  asm volatile("s_waitcnt vmcnt(0)" ::: "memory");

  // epilogue: SiLU(acc * 2^-19) -> 2-plane f16 split (x256)
  const float sc = 1.0f / (256.0f * 2048.0f);
  const int r0 = bm + ha * 128 + ((l >> 4) << 2);
  const int c0 = bn + wc + (l & 15);
#pragma unroll
  for (int mh = 0; mh < 2; ++mh)
#pragma unroll
    for (int mf = 0; mf < 4; ++mf)
#pragma unroll
      for (int i = 0; i < 4; ++i) {
        const int row = r0 + mh * 64 + mf * 16 + i;
#pragma unroll
        for (int nh = 0; nh < 2; ++nh)
#pragma unroll
          for (int nf = 0; nf < 2; ++nf) {
            const int col = c0 + nh * 32 + nf * 16;
            float v = acc[mh][nh][mf][nf][i] * sc;
            v = v / (1.0f + expf(-v));          // SiLU, precision path
            float t = v * 256.0f;
            f16 h0 = (f16)t;
            O0[(size_t)row * N + col] = h0;
            O1[(size_t)row * N + col] = (f16)(t - (float)h0);
          }
      }
}

// ---------------------------------------------------------------------------
// row layernorm + relu, in place; block per row
// ---------------------------------------------------------------------------
template <int VPT, typename T>
__global__ __launch_bounds__(256) void ln_relu(T* __restrict__ x,
    const float* __restrict__ g, const float* __restrict__ b) {
  const int N = VPT * 256;
  const size_t base = (size_t)blockIdx.x * N;
  const int tid = threadIdx.x, w = tid >> 6, l = tid & 63;
  float v[VPT];
#pragma unroll
  for (int q = 0; q < VPT; ++q) v[q] = (float)x[base + q * 256 + tid];
  float s = 0.0f;
#pragma unroll
  for (int q = 0; q < VPT; ++q) s += v[q];
#pragma unroll
  for (int m = 1; m < 64; m <<= 1) s += __shfl_xor(s, m, 64);
  __shared__ float red[8];
  if (l == 0) red[w] = s;
  __syncthreads();
  float mean = (red[0] + red[1] + red[2] + red[3]) * (1.0f / N);
  float ss = 0.0f;
#pragma unroll
  for (int q = 0; q < VPT; ++q) { float t = v[q] - mean; ss += t * t; }
#pragma unroll
  for (int m = 1; m < 64; m <<= 1) ss += __shfl_xor(ss, m, 64);
  if (l == 0) red[4 + w] = ss;
  __syncthreads();
  float var = (red[4] + red[5] + red[6] + red[7]) * (1.0f / N);
  float rs = 1.0f / sqrtf(var + 1e-5f);
#pragma unroll
  for (int q = 0; q < VPT; ++q) {
    int j = q * 256 + tid;
    float y = (v[q] - mean) * rs * g[j] + b[j];
    x[base + j] = (T)fmaxf(y, 0.0f);
  }
}

// ---------------------------------------------------------------------------
// launch
// ---------------------------------------------------------------------------
extern "C" void kernel_launch(void* const* d_in, const int* in_sizes, int n_in,
                              void* d_out, int out_size, void* d_ws, size_t ws_size,
                              hipStream_t stream) {
  (void)in_sizes; (void)n_in; (void)out_size; (void)ws_size;
  const float* semI  = (const float*)d_in[0];
  const float* colI  = (const float*)d_in[1];
  const float* gw1   = (const float*)d_in[2];
  const float* gb1   = (const float*)d_in[3];
  const float* glng  = (const float*)d_in[4];
  const float* glnb  = (const float*)d_in[5];
  const float* gw2   = (const float*)d_in[6];
  const float* gb2   = (const float*)d_in[7];
  const float* fg    = (const float*)d_in[8];
  const float* fb    = (const float*)d_in[9];
  const float* ew1   = (const float*)d_in[10];
  const float* ew2   = (const float*)d_in[11];
  const float* ew3   = (const float*)d_in[12];
  const float* ew4   = (const float*)d_in[13];
  const float* dw1   = (const float*)d_in[14];
  const float* dw2   = (const float*)d_in[15];
  const float* dw3   = (const float*)d_in[16];
  const float* sw1   = (const float*)d_in[17];
  const float* sb1   = (const float*)d_in[18];
  const float* slng  = (const float*)d_in[19];
  const float* slnb  = (const float*)d_in[20];
  const float* sw2   = (const float*)d_in[21];
  const float* sb2   = (const float*)d_in[22];
  const float* cw1   = (const float*)d_in[23];
  const float* cb1   = (const float*)d_in[24];
  const float* clng  = (const float*)d_in[25];
  const float* clnb  = (const float*)d_in[26];
  const float* cw2   = (const float*)d_in[27];
  const float* cb2   = (const float*)d_in[28];
  const float* cbk   = (const float*)d_in[29];

  float* out = (float*)d_out;
  char* ws = (char*)d_ws;

  // output offsets (floats)
  const size_t OUT_SEM = 0, OUT_COL = 50331648, OUT_ZQ = 54525952,
               OUT_CODES = 58720256, OUT_CB = 58916864, OUT_GATE = 58916866;

  // ws layout (bytes)
  bf16* dec1t = (bf16*)(ws + 0);
  bf16* dec2t = (bf16*)(ws + 16384);
  bf16* dec3t = (bf16*)(ws + 81920);
  bf16* sem1t = (bf16*)(ws + 344064);
  bf16* sem2t = (bf16*)(ws + 1916928);
  bf16* col1t = (bf16*)(ws + 4276224);
  float* cbT  = (float*)(ws + 4538368);
  float* nhn  = (float*)(ws + 4734976);
  f16* e1w0   = (f16*)(ws + 4739072);
  f16* e1w1   = (f16*)(ws + 5591040);
  f16* e2w0   = (f16*)(ws + 6443008);
  f16* e2w1   = (f16*)(ws + 6705152);
  f16* e3w0   = (f16*)(ws + 6967296);
  f16* e3w1   = (f16*)(ws + 7032832);
  const size_t WS_A = 8388608, WS_B = 226492416;
  // fused planes occupy exactly the old fp32 fused footprint (218103808 B)
  f16* fA0 = (f16*)(ws + WS_A);
  f16* fA1 = (f16*)(ws + WS_A + 109051904);
  float* scores = (float*)(ws + WS_A);            // reuses fused after E1
  bf16*  semh   = (bf16*)(ws + WS_A);             // reuses scores after RQ
  float* den = (float*)(ws + WS_B);               // pre-E1 temp
  float* hn  = (float*)(ws + WS_B + 16777216);    // pre-E1 temp
  // h1/h2 planes in the old fp32 footprints
  f16* h1a = (f16*)(ws + WS_B);
  f16* h1b = (f16*)(ws + WS_B + 67108864);
  f16* h2a = (f16*)(ws + 360710144);
  f16* h2b = (f16*)(ws + 360710144 + 33554432);
  float* h3  = (float*)(ws + 427819008);
  float* rn  = (float*)(ws + 461373440);
  bf16* zqb  = (bf16*)(ws + WS_B);
  bf16* d1b  = (bf16*)(ws + WS_B + 8388608);
  bf16* d2b  = (bf16*)(ws + WS_B + 25165824);
  bf16* sb   = (bf16*)(ws + WS_B + 58720256);
  float* colh = (float*)(ws + WS_B + 125829120);

  // zero the two loss scalars (d_out is poisoned each launch)
  hipMemsetAsync(out + OUT_CB, 0, 2 * sizeof(float), stream);

  // weight prep
  wconv_t<<<(64 * 128 + 255) / 256, 256, 0, stream>>>(dw1, dec1t, 64, 128);
  wconv_t<<<(128 * 256 + 255) / 256, 256, 0, stream>>>(dw2, dec2t, 128, 256);
  wconv_t<<<(256 * 512 + 255) / 256, 256, 0, stream>>>(dw3, dec3t, 256, 512);
  wconv_t<<<(512 * 1536 + 255) / 256, 256, 0, stream>>>(sw1, sem1t, 512, 1536);
  wconv_t<<<(1536 * 768 + 255) / 256, 256, 0, stream>>>(sw2, sem2t, 1536, 768);
  wconv_t<<<(512 * 256 + 255) / 256, 256, 0, stream>>>(cw1, col1t, 512, 256);
  wsplit_t<<<(832 * 512 + 255) / 256, 256, 0, stream>>>(ew1, e1w0, e1w1, 832, 512);
  wsplit_t<<<(512 * 256 + 255) / 256, 256, 0, stream>>>(ew2, e2w0, e2w1, 512, 256);
  wsplit_t<<<(256 * 128 + 255) / 256, 256, 0, stream>>>(ew3, e3w0, e3w1, 256, 128);
  cbt_k<<<192, 256, 0, stream>>>(cbk, cbT);
  nhn_k<<<3, 256, 0, stream>>>(cbk, nhn);

  // gate network (fp32)
  sgemm128<2><<<dim3(1, 512), 256, 0, stream>>>(colI, gw1, gb1, glng, glnb, hn, 128, 64);
  sgemm64<2><<<512, 256, 0, stream>>>(hn, gw2, gb2, colI, out + OUT_GATE, den, 128);
  fuse_ln<<<4096, 256, 0, stream>>>(semI, den, fg, fb, fA0, fA1);

  // encoder (fp32-accurate via pre-split fp16 planes, 256^2 8-phase MFMA)
  hgemm38<<<dim3(2, 256), 512, 0, stream>>>(fA0, fA1, e1w0, e1w1, h1a, h1b, 512, 832);
  hgemm38<<<dim3(1, 256), 512, 0, stream>>>(h1a, h1b, e2w0, e2w1, h2a, h2b, 256, 512);
  hgemm_p<<<dim3(1, 512), 256, 0, stream>>>(h2a, h2b, e3w0, e3w1, h3, 128, 256);
  sgemm64<0><<<512, 256, 0, stream>>>(h3, ew4, nullptr, nullptr, rn, nullptr, 128);

  // residual quantization (fp32 scores as GEMM + argmax/update)
  sgemm128<1><<<dim3(2, 512), 256, 0, stream>>>(rn, cbT + 0 * 16384, nhn + 0, nullptr, nullptr, scores, 256, 64);
  argupd<0><<<1024, 256, 0, stream>>>(scores, cbk + 0 * 16384, rn, out + OUT_ZQ, out + OUT_CODES, out + OUT_CB, zqb);
  sgemm128<1><<<dim3(2, 512), 256, 0, stream>>>(rn, cbT + 1 * 16384, nhn + 256, nullptr, nullptr, scores, 256, 64);
  argupd<1><<<1024, 256, 0, stream>>>(scores, cbk + 1 * 16384, rn, out + OUT_ZQ, out + OUT_CODES, out + OUT_CB, zqb);
  sgemm128<1><<<dim3(2, 512), 256, 0, stream>>>(rn, cbT + 2 * 16384, nhn + 512, nullptr, nullptr, scores, 256, 64);
  argupd<2><<<1024, 256, 0, stream>>>(scores, cbk + 2 * 16384, rn, out + OUT_ZQ, out + OUT_CODES, out + OUT_CB, zqb);

  // decoder + heads (bf16 MFMA; big GEMMs on the 256^2 8-phase structure)
  bgemm<0><<<dim3(1, 512), 256, 0, stream>>>(zqb, dec1t, nullptr, d1b, 128, 64);
  bgemm8<0><<<dim3(1, 256), 512, 0, stream>>>(d1b, dec2t, nullptr, d2b, 256, 128);
  bgemm8<0><<<dim3(2, 256), 512, 0, stream>>>(d2b, dec3t, nullptr, sb, 512, 256);
  bgemm8<1><<<dim3(6, 256), 512, 0, stream>>>(sb, sem1t, sb1, semh, 1536, 512);
  ln_relu<6, bf16><<<65536, 256, 0, stream>>>(semh, slng, slnb);
  bgemm8<2><<<dim3(3, 256), 512, 0, stream>>>(semh, sem2t, sb2, out + OUT_SEM, 768, 1536);
  bgemm8<2><<<dim3(1, 256), 512, 0, stream>>>(sb, col1t, cb1, colh, 256, 512);
  ln_relu<1, float><<<65536, 256, 0, stream>>>(colh, clng, clnb);
  sgemm64<1><<<512, 256, 0, stream>>>(colh, cw2, cb2, nullptr, out + OUT_COL, nullptr, 256);
}

// Round 4
// 1913.013 us; speedup vs baseline: 1.0963x; 1.0963x over previous
//
#include <hip/hip_runtime.h>
#include <hip/hip_bf16.h>
#include <math.h>

typedef __bf16 bf16;
typedef __attribute__((ext_vector_type(8))) __bf16 v8bf;
typedef __attribute__((ext_vector_type(4))) float v4f;
typedef _Float16 f16;
typedef __attribute__((ext_vector_type(8))) _Float16 v8h;
typedef __attribute__((ext_vector_type(4))) _Float16 v4h;

// XCD-ownership block swizzle (128 tiles). Requires gridDim.y % 8 == 0.
__device__ __forceinline__ void xcd_swizzle(int& bm, int& bn) {
  const int nx = gridDim.x;
  const int id = blockIdx.y * nx + blockIdx.x;
  const int slot = id >> 3;
  const int row_in = slot / nx;
  const int bmi = (id & 7) * (gridDim.y >> 3) + row_in;
  const int bni = slot - row_in * nx;
  bm = bmi << 7; bn = bni << 7;
}

// same, 256x256 tiles
__device__ __forceinline__ void xcd_swizzle256(int& bm, int& bn) {
  const int nx = gridDim.x;
  const int id = blockIdx.y * nx + blockIdx.x;
  const int slot = id >> 3;
  const int row_in = slot / nx;
  const int bmi = (id & 7) * (gridDim.y >> 3) + row_in;
  const int bni = slot - row_in * nx;
  bm = bmi << 8; bn = bni << 8;
}

// ---------------------------------------------------------------------------
// small prep kernels
// ---------------------------------------------------------------------------
__global__ void wconv_t(const float* __restrict__ W, bf16* __restrict__ Wt, int Kd, int Nd) {
  int e = blockIdx.x * 256 + threadIdx.x;
  if (e < Kd * Nd) {
    int k = e / Nd, n = e - k * Nd;
    Wt[n * Kd + k] = (bf16)W[e];   // store transposed [N][K] for gemm_bt
  }
}

// fp32 -> 2-plane fp16 split, transposed, pre-scaled by 2048
__global__ void wsplit_t(const float* __restrict__ W, f16* __restrict__ W0,
                         f16* __restrict__ W1, int Kd, int Nd) {
  int e = blockIdx.x * 256 + threadIdx.x;
  if (e < Kd * Nd) {
    int k = e / Nd, n = e - k * Nd;
    float v = W[e] * 2048.0f;
    f16 h0 = (f16)v;
    f16 h1 = (f16)(v - (float)h0);
    W0[n * Kd + k] = h0;
    W1[n * Kd + k] = h1;
  }
}

__global__ void cbt_k(const float* __restrict__ cb, float* __restrict__ cbT) {
  int e = blockIdx.x * 256 + threadIdx.x;   // 3*256*64 total
  if (e < 3 * 256 * 64) {
    int l = e >> 14, rem = e & 16383;
    int c = rem >> 6, d = rem & 63;
    cbT[l * 16384 + d * 256 + c] = cb[e];   // [l][d][c]
  }
}

__global__ void nhn_k(const float* __restrict__ cb, float* __restrict__ nhn) {
  int l = blockIdx.x, c = threadIdx.x;      // grid 3 x 256
  const float* p = cb + l * 16384 + c * 64;
  double s = 0.0;
  for (int d = 0; d < 64; ++d) { double v = (double)p[d]; s += v * v; }
  nhn[l * 256 + c] = (float)(-0.5 * s);
}

// ---------------------------------------------------------------------------
// fp32 GEMM, 128x128 tile, BK=32, 8x8 per thread.
// EPI: 0 = SiLU->f32, 1 = +bias->f32, 2 = +bias, LN(128), ReLU -> f32 (needs gridDim.x==1,N==128)
// ---------------------------------------------------------------------------
template <int EPI>
__global__ __launch_bounds__(256, 2) void sgemm128(
    const float* __restrict__ A, const float* __restrict__ W,
    const float* __restrict__ bias, const float* __restrict__ lng,
    const float* __restrict__ lnb, float* __restrict__ C, int N, int Kd) {
  __shared__ float As[32][132];   // [k][m], padded
  __shared__ float Bs[32][128];   // [k][n]
  const int tid = threadIdx.x;
  const int w = tid >> 6, l = tid & 63;
  int tx, ty;
  if (EPI == 2) { tx = tid & 15; ty = tid >> 4; }
  else { tx = ((w & 1) << 3) | (l & 7); ty = ((w >> 1) << 3) | (l >> 3); }
  int bm, bn;
  xcd_swizzle(bm, bn);

  float acc[8][8];
#pragma unroll
  for (int i = 0; i < 8; ++i)
#pragma unroll
    for (int j = 0; j < 8; ++j) acc[i][j] = 0.0f;

  for (int k0 = 0; k0 < Kd; k0 += 32) {
    __syncthreads();
#pragma unroll
    for (int jj = 0; jj < 4; ++jj) {
      int p = tid + 256 * jj;
      int arow = p >> 3, aks = (p & 7) << 2;
      float4 v = *(const float4*)(A + (size_t)(bm + arow) * Kd + k0 + aks);
      As[aks][arow] = v.x; As[aks + 1][arow] = v.y;
      As[aks + 2][arow] = v.z; As[aks + 3][arow] = v.w;
      int bk = p >> 5, bns = (p & 31) << 2;
      float4 u = *(const float4*)(W + (size_t)(k0 + bk) * N + bn + bns);
      *(float4*)(&Bs[bk][bns]) = u;
    }
    __syncthreads();
    float cacc[8][8];
#pragma unroll
    for (int i = 0; i < 8; ++i)
#pragma unroll
      for (int j = 0; j < 8; ++j) cacc[i][j] = 0.0f;
#pragma unroll 4
    for (int kk = 0; kk < 32; ++kk) {
      float a[8], b[8];
#pragma unroll
      for (int i = 0; i < 8; ++i) a[i] = As[kk][ty * 8 + i];
#pragma unroll
      for (int j = 0; j < 8; ++j) b[j] = Bs[kk][tx * 8 + j];
#pragma unroll
      for (int i = 0; i < 8; ++i)
#pragma unroll
        for (int j = 0; j < 8; ++j) cacc[i][j] = fmaf(a[i], b[j], cacc[i][j]);
    }
#pragma unroll
    for (int i = 0; i < 8; ++i)
#pragma unroll
      for (int j = 0; j < 8; ++j) acc[i][j] += cacc[i][j];
  }

  const int colb = bn + tx * 8;
  if (EPI == 0) {
#pragma unroll
    for (int i = 0; i < 8; ++i) {
      int row = bm + ty * 8 + i;
      float o[8];
#pragma unroll
      for (int j = 0; j < 8; ++j) { float v = acc[i][j]; o[j] = v / (1.0f + expf(-v)); }
      *(float4*)(C + (size_t)row * N + colb) = make_float4(o[0], o[1], o[2], o[3]);
      *(float4*)(C + (size_t)row * N + colb + 4) = make_float4(o[4], o[5], o[6], o[7]);
    }
  } else if (EPI == 1) {
    float bb[8];
#pragma unroll
    for (int j = 0; j < 8; ++j) bb[j] = bias[colb + j];
#pragma unroll
    for (int i = 0; i < 8; ++i) {
      int row = bm + ty * 8 + i;
      float o[8];
#pragma unroll
      for (int j = 0; j < 8; ++j) o[j] = acc[i][j] + bb[j];
      *(float4*)(C + (size_t)row * N + colb) = make_float4(o[0], o[1], o[2], o[3]);
      *(float4*)(C + (size_t)row * N + colb + 4) = make_float4(o[4], o[5], o[6], o[7]);
    }
  } else {
    float bb[8], lg[8], lb[8];
#pragma unroll
    for (int j = 0; j < 8; ++j) { bb[j] = bias[colb + j]; lg[j] = lng[colb + j]; lb[j] = lnb[colb + j]; }
#pragma unroll
    for (int i = 0; i < 8; ++i) {
      int row = bm + ty * 8 + i;
      float v[8]; float s = 0.0f;
#pragma unroll
      for (int j = 0; j < 8; ++j) { v[j] = acc[i][j] + bb[j]; s += v[j]; }
      s += __shfl_xor(s, 1); s += __shfl_xor(s, 2); s += __shfl_xor(s, 4); s += __shfl_xor(s, 8);
      float mean = s * (1.0f / 128.0f);
      float ss = 0.0f;
#pragma unroll
      for (int j = 0; j < 8; ++j) { float t = v[j] - mean; ss += t * t; }
      ss += __shfl_xor(ss, 1); ss += __shfl_xor(ss, 2); ss += __shfl_xor(ss, 4); ss += __shfl_xor(ss, 8);
      float rs = 1.0f / sqrtf(ss * (1.0f / 128.0f) + 1e-5f);
      float o[8];
#pragma unroll
      for (int j = 0; j < 8; ++j) o[j] = fmaxf((v[j] - mean) * rs * lg[j] + lb[j], 0.0f);
      *(float4*)(C + (size_t)row * N + colb) = make_float4(o[0], o[1], o[2], o[3]);
      *(float4*)(C + (size_t)row * N + colb + 4) = make_float4(o[4], o[5], o[6], o[7]);
    }
  }
}

// ---------------------------------------------------------------------------
// fp32 GEMM, 128x64 tile (N fixed 64), BK=32, 8x4 per thread.
// EPI: 0 = l2norm row -> C, 1 = +bias -> C, 2 = gate (sigmoid->C, gate*aux->C2)
// ---------------------------------------------------------------------------
template <int EPI>
__global__ __launch_bounds__(256, 2) void sgemm64(
    const float* __restrict__ A, const float* __restrict__ W,
    const float* __restrict__ bias, const float* __restrict__ aux,
    float* __restrict__ C, float* __restrict__ C2, int Kd) {
  __shared__ float As[32][132];
  __shared__ float Bs[32][64];
  const int tid = threadIdx.x;
  const int tx = tid & 15, ty = tid >> 4;
  const int bm = blockIdx.x << 7;

  float acc[8][4];
#pragma unroll
  for (int i = 0; i < 8; ++i)
#pragma unroll
    for (int j = 0; j < 4; ++j) acc[i][j] = 0.0f;

  for (int k0 = 0; k0 < Kd; k0 += 32) {
    __syncthreads();
#pragma unroll
    for (int jj = 0; jj < 4; ++jj) {
      int p = tid + 256 * jj;
      int arow = p >> 3, aks = (p & 7) << 2;
      float4 v = *(const float4*)(A + (size_t)(bm + arow) * Kd + k0 + aks);
      As[aks][arow] = v.x; As[aks + 1][arow] = v.y;
      As[aks + 2][arow] = v.z; As[aks + 3][arow] = v.w;
    }
#pragma unroll
    for (int jj = 0; jj < 2; ++jj) {
      int p = tid + 256 * jj;
      int bk = p >> 4, bns = (p & 15) << 2;
      float4 u = *(const float4*)(W + (size_t)(k0 + bk) * 64 + bns);
      *(float4*)(&Bs[bk][bns]) = u;
    }
    __syncthreads();
    float cacc[8][4];
#pragma unroll
    for (int i = 0; i < 8; ++i)
#pragma unroll
      for (int j = 0; j < 4; ++j) cacc[i][j] = 0.0f;
#pragma unroll 4
    for (int kk = 0; kk < 32; ++kk) {
      float a[8], b[4];
#pragma unroll
      for (int i = 0; i < 8; ++i) a[i] = As[kk][ty * 8 + i];
#pragma unroll
      for (int j = 0; j < 4; ++j) b[j] = Bs[kk][tx * 4 + j];
#pragma unroll
      for (int i = 0; i < 8; ++i)
#pragma unroll
        for (int j = 0; j < 4; ++j) cacc[i][j] = fmaf(a[i], b[j], cacc[i][j]);
    }
#pragma unroll
    for (int i = 0; i < 8; ++i)
#pragma unroll
      for (int j = 0; j < 4; ++j) acc[i][j] += cacc[i][j];
  }

  const int colb = tx * 4;
  if (EPI == 0) {           // l2norm(z) -> rn
#pragma unroll
    for (int i = 0; i < 8; ++i) {
      int row = bm + ty * 8 + i;
      float ss = 0.0f;
#pragma unroll
      for (int j = 0; j < 4; ++j) ss += acc[i][j] * acc[i][j];
      ss += __shfl_xor(ss, 1); ss += __shfl_xor(ss, 2); ss += __shfl_xor(ss, 4); ss += __shfl_xor(ss, 8);
      float nrm = fmaxf(sqrtf(ss), 1e-12f);
      *(float4*)(C + (size_t)row * 64 + colb) =
          make_float4(acc[i][0] / nrm, acc[i][1] / nrm, acc[i][2] / nrm, acc[i][3] / nrm);
    }
  } else if (EPI == 1) {
    float bb[4];
#pragma unroll
    for (int j = 0; j < 4; ++j) bb[j] = bias[colb + j];
#pragma unroll
    for (int i = 0; i < 8; ++i) {
      int row = bm + ty * 8 + i;
      *(float4*)(C + (size_t)row * 64 + colb) =
          make_float4(acc[i][0] + bb[0], acc[i][1] + bb[1], acc[i][2] + bb[2], acc[i][3] + bb[3]);
    }
  } else {                  // gate: sigmoid -> C (gate_values), gate*collab -> C2 (denoised)
    float bb[4];
#pragma unroll
    for (int j = 0; j < 4; ++j) bb[j] = bias[colb + j];
#pragma unroll
    for (int i = 0; i < 8; ++i) {
      int row = bm + ty * 8 + i;
      float4 av = *(const float4*)(aux + (size_t)row * 64 + colb);
      float g[4];
#pragma unroll
      for (int j = 0; j < 4; ++j) g[j] = 1.0f / (1.0f + expf(-(acc[i][j] + bb[j])));
      *(float4*)(C + (size_t)row * 64 + colb) = make_float4(g[0], g[1], g[2], g[3]);
      *(float4*)(C2 + (size_t)row * 64 + colb) =
          make_float4(g[0] * av.x, g[1] * av.y, g[2] * av.z, g[3] * av.w);
    }
  }
}

// ---------------------------------------------------------------------------
// fusion layernorm over 832; wave per row. Emits the 2-plane f16 split of the
// normalized row (x256 scale) so the encoder GEMM consumes pure f16 planes.
// (verified round 3: bitwise-equal to the old per-tile split)
// ---------------------------------------------------------------------------
__global__ __launch_bounds__(256) void fuse_ln(
    const float* __restrict__ sem, const float* __restrict__ den,
    const float* __restrict__ fg, const float* __restrict__ fb,
    f16* __restrict__ fA0, f16* __restrict__ fA1) {
  const int w = threadIdx.x >> 6, l = threadIdx.x & 63;
  float fgv[13], fbv[13];
#pragma unroll
  for (int q = 0; q < 12; ++q) { fgv[q] = fg[q * 64 + l]; fbv[q] = fb[q * 64 + l]; }
  fgv[12] = fg[768 + l]; fbv[12] = fb[768 + l];
  for (int it = 0; it < 4; ++it) {
    int r = (blockIdx.x * 4 + w) * 4 + it;
    float sv[12];
#pragma unroll
    for (int q = 0; q < 12; ++q) sv[q] = sem[(size_t)r * 768 + q * 64 + l];
    float dv = den[(size_t)r * 64 + l];
    float s = dv;
#pragma unroll
    for (int q = 0; q < 12; ++q) s += sv[q];
#pragma unroll
    for (int m = 1; m < 64; m <<= 1) s += __shfl_xor(s, m, 64);
    float mean = s * (1.0f / 832.0f);
    float t0 = dv - mean;
    float ss = t0 * t0;
#pragma unroll
    for (int q = 0; q < 12; ++q) { float t = sv[q] - mean; ss += t * t; }
#pragma unroll
    for (int m = 1; m < 64; m <<= 1) ss += __shfl_xor(ss, m, 64);
    float sc = 1.0f / sqrtf(ss * (1.0f / 832.0f) + 1e-5f);
#pragma unroll
    for (int q = 0; q < 13; ++q) {
      float y = (q < 12) ? ((sv[q] - mean) * sc * fgv[q] + fbv[q])
                         : (t0 * sc * fgv[12] + fbv[12]);
      float t = y * 256.0f;
      f16 h0 = (f16)t;
      size_t idx = (size_t)r * 832 + q * 64 + l;
      fA0[idx] = h0;
      fA1[idx] = (f16)(t - (float)h0);
    }
  }
}

// ---------------------------------------------------------------------------
// RQ argmax + update; wave per row, 16 rows/wave
// ---------------------------------------------------------------------------
template <int LAYER>
__global__ __launch_bounds__(256) void argupd(
    const float* __restrict__ scores, const float* __restrict__ cbl,
    float* __restrict__ rn, float* __restrict__ zq, float* __restrict__ codes,
    float* __restrict__ loss, bf16* __restrict__ zqb) {
  const int w = threadIdx.x >> 6, l = threadIdx.x & 63;
  const int base = (blockIdx.x * 4 + w) * 16;
  float lacc = 0.0f;
  for (int it = 0; it < 16; ++it) {
    int r = base + it;
    float4 s4 = *(const float4*)(scores + (size_t)r * 256 + l * 4);
    float bs = s4.x; int bi = l * 4;
    if (s4.y > bs) { bs = s4.y; bi = l * 4 + 1; }
    if (s4.z > bs) { bs = s4.z; bi = l * 4 + 2; }
    if (s4.w > bs) { bs = s4.w; bi = l * 4 + 3; }
#pragma unroll
    for (int m = 1; m < 64; m <<= 1) {
      float os = __shfl_xor(bs, m, 64);
      int oi = __shfl_xor(bi, m, 64);
      if (os > bs || (os == bs && oi < bi)) { bs = os; bi = oi; }
    }
    float e = cbl[bi * 64 + l];
    float rl = rn[(size_t)r * 64 + l];
    float emr = e - rl;
    float zql = rl + emr;          // straight-through forward value, ref rounding order
    lacc += emr * emr;
    if (l == 0) codes[r * 3 + LAYER] = (float)bi;
    if (LAYER == 0) {
      zq[(size_t)r * 64 + l] = zql;
    } else if (LAYER == 1) {
      zq[(size_t)r * 64 + l] += zql;
    } else {
      float tot = zq[(size_t)r * 64 + l] + zql;
      zq[(size_t)r * 64 + l] = tot;
      zqb[(size_t)r * 64 + l] = (bf16)tot;
    }
    if (LAYER < 2) {
      float rnew = rl - zql;
      float ss = rnew * rnew;
#pragma unroll
      for (int m = 1; m < 64; m <<= 1) ss += __shfl_xor(ss, m, 64);
      float nrm = fmaxf(sqrtf(ss), 1e-12f);
      rn[(size_t)r * 64 + l] = rnew / nrm;
    }
  }
#pragma unroll
  for (int m = 1; m < 64; m <<= 1) lacc += __shfl_xor(lacc, m, 64);
  if (l == 0) {
    float v = lacc * (1.0f / 4194304.0f);   // 1/(65536*64), exact pow2
    atomicAdd(loss, v);
    atomicAdd(loss + 1, v);
  }
}

// ---------------------------------------------------------------------------
// async global->LDS helper
// ---------------------------------------------------------------------------
typedef __attribute__((address_space(3))) void lds_void_t;
typedef __attribute__((address_space(1))) const void gbl_void_t;
__device__ __forceinline__ void gl_lds16(const void* g, void* l) {
  __builtin_amdgcn_global_load_lds((gbl_void_t*)g, (lds_void_t*)l, 16, 0, 0);
}

// ---------------------------------------------------------------------------
// bf16 MFMA GEMM (m97 structure): 128x128 tile, BK=32 (kept for N=128 case)
// EPI: 0 = SiLU->bf16, 1 = +bias->bf16, 2 = +bias->f32
// ---------------------------------------------------------------------------
template <int EPI>
__global__ __launch_bounds__(256, 3) void bgemm(
    const bf16* __restrict__ A, const bf16* __restrict__ Wt,
    const float* __restrict__ bias, void* __restrict__ Cv, int N, int Kd) {
  __shared__ __align__(16) bf16 As[128 * 32];
  __shared__ __align__(16) bf16 Bs[128 * 32];
  const int tid = threadIdx.x;
  const int w = tid >> 6, l = tid & 63;
  int bm, bn;
  xcd_swizzle(bm, bn);
  const int wm = (w >> 1) << 6, wn = (w & 1) << 6;

  v4f acc[4][4];
  v4f z4 = {0.0f, 0.0f, 0.0f, 0.0f};
#pragma unroll
  for (int i = 0; i < 4; ++i)
#pragma unroll
    for (int j = 0; j < 4; ++j) acc[i][j] = z4;

  const int srow = (w << 5) + (l >> 2);
  const int skc = (l & 3) << 3;
  const bf16* ga0 = A + (size_t)(bm + srow) * Kd + skc;
  const bf16* gb0 = Wt + (size_t)(bn + srow) * Kd + skc;
  char* la0 = (char*)As + (w << 11);
  char* lb0 = (char*)Bs + (w << 11);

  for (int k0 = 0; k0 < Kd; k0 += 32) {
    __syncthreads();
    gl_lds16(ga0 + k0, la0);
    gl_lds16(ga0 + (size_t)16 * Kd + k0, la0 + 1024);
    gl_lds16(gb0 + k0, lb0);
    gl_lds16(gb0 + (size_t)16 * Kd + k0, lb0 + 1024);
    __syncthreads();
    v8bf af[4], bfr[4];
#pragma unroll
    for (int f = 0; f < 4; ++f) {
      af[f] = *(const v8bf*)(As + (wm + f * 16 + (l & 15)) * 32 + ((l >> 4) << 3));
      bfr[f] = *(const v8bf*)(Bs + (wn + f * 16 + (l & 15)) * 32 + ((l >> 4) << 3));
    }
#pragma unroll
    for (int mf = 0; mf < 4; ++mf)
#pragma unroll
      for (int nf = 0; nf < 4; ++nf)
        acc[mf][nf] = __builtin_amdgcn_mfma_f32_16x16x32_bf16(af[mf], bfr[nf], acc[mf][nf], 0, 0, 0);
  }

  const int cbase = bn + wn + (l & 15);
  float bb[4];
  if (EPI != 0) {
#pragma unroll
    for (int nf = 0; nf < 4; ++nf) bb[nf] = bias[cbase + nf * 16];
  }
#pragma unroll
  for (int mf = 0; mf < 4; ++mf) {
#pragma unroll
    for (int i = 0; i < 4; ++i) {
      int row = bm + wm + mf * 16 + ((l >> 4) << 2) + i;
#pragma unroll
      for (int nf = 0; nf < 4; ++nf) {
        int col = cbase + nf * 16;
        float v = acc[mf][nf][i];
        if (EPI == 0) {
          v = v / (1.0f + __expf(-v));
          ((bf16*)Cv)[(size_t)row * N + col] = (bf16)v;
        } else if (EPI == 1) {
          v += bb[nf];
          ((bf16*)Cv)[(size_t)row * N + col] = (bf16)v;
        } else {
          v += bb[nf];
          ((float*)Cv)[(size_t)row * N + col] = v;
        }
      }
    }
  }
}

// ---------------------------------------------------------------------------
// plane staging + swizzled LDS read (verified round 3: 0 bank conflicts).
// 64B rows; swizzle: byte bits 4-5 ^= row bits 1-2 (involution), applied to
// the pre-swizzled global source chunk and to the ds_read_b128 address.
// Works for any wave count: wave wid stages chunks [wid*128, wid*128+128).
// ---------------------------------------------------------------------------
__device__ __forceinline__ void stage_plane(const f16* __restrict__ src, int Kd,
                                            int rbase, int k0, char* base,
                                            int wid, int l) {
#pragma unroll
  for (int j = 0; j < 2; ++j) {
    int Cc = wid * 128 + j * 64 + l;
    int cc = Cc ^ ((Cc >> 3) & 3);
    gl_lds16(src + (size_t)(rbase + (cc >> 2)) * Kd + k0 + (cc & 3) * 8,
             base + wid * 2048 + j * 1024);
  }
}

__device__ __forceinline__ v8h ldsfragh(const char* base, int row, int kb) {
  int p = row * 64 + kb;
  p ^= ((p >> 7) & 3) << 4;
  return *(const v8h*)(base + p);
}

// ---------------------------------------------------------------------------
// f16 2-plane GEMM, 128x128 tile, BK=32, m97 structure (3 blocks/CU), fed by
// pre-split planes via global_load_lds — NO VALU split in the K-loop, and
// conflict-free swizzled LDS reads. MFMA product order identical to hgemm3
// (a0*b1, a1*b0, a0*b0) -> bitwise-equal accumulation.
// EPI: 0 = SiLU -> 2-plane f16 split (x256) for the next layer
//      1 = SiLU -> fp32
// ---------------------------------------------------------------------------
template <int EPI>
__global__ __launch_bounds__(256, 3) void hgemmp(
    const f16* __restrict__ A0, const f16* __restrict__ A1,
    const f16* __restrict__ W0, const f16* __restrict__ W1,
    f16* __restrict__ O0, f16* __restrict__ O1, float* __restrict__ Cf,
    int N, int Kd) {
  __shared__ __align__(16) char smem[32768];   // 4 planes x 8KB: A0,A1,B0,B1
  const int tid = threadIdx.x;
  const int w = tid >> 6, l = tid & 63;
  int bm, bn;
  xcd_swizzle(bm, bn);
  const int wm = (w >> 1) << 6, wn = (w & 1) << 6;
  const int kb = (l >> 4) << 4;   // byte offset within 64B row

  char* pa0 = smem;
  char* pa1 = smem + 8192;
  char* pb0 = smem + 16384;
  char* pb1 = smem + 24576;

  v4f acc[4][4];
  v4f z4 = {0.0f, 0.0f, 0.0f, 0.0f};
#pragma unroll
  for (int i = 0; i < 4; ++i)
#pragma unroll
    for (int j = 0; j < 4; ++j) acc[i][j] = z4;

  for (int k0 = 0; k0 < Kd; k0 += 32) {
    __syncthreads();
    stage_plane(A0, Kd, bm, k0, pa0, w, l);
    stage_plane(A1, Kd, bm, k0, pa1, w, l);
    stage_plane(W0, Kd, bn, k0, pb0, w, l);
    stage_plane(W1, Kd, bn, k0, pb1, w, l);
    __syncthreads();
    v8h a0f[4], a1f[4], b0f[4], b1f[4];
#pragma unroll
    for (int f = 0; f < 4; ++f) {
      a0f[f] = ldsfragh(pa0, wm + f * 16 + (l & 15), kb);
      a1f[f] = ldsfragh(pa1, wm + f * 16 + (l & 15), kb);
      b0f[f] = ldsfragh(pb0, wn + f * 16 + (l & 15), kb);
      b1f[f] = ldsfragh(pb1, wn + f * 16 + (l & 15), kb);
    }
#pragma unroll
    for (int mf = 0; mf < 4; ++mf)
#pragma unroll
      for (int nf = 0; nf < 4; ++nf) {
        acc[mf][nf] = __builtin_amdgcn_mfma_f32_16x16x32_f16(a0f[mf], b1f[nf], acc[mf][nf], 0, 0, 0);
        acc[mf][nf] = __builtin_amdgcn_mfma_f32_16x16x32_f16(a1f[mf], b0f[nf], acc[mf][nf], 0, 0, 0);
        acc[mf][nf] = __builtin_amdgcn_mfma_f32_16x16x32_f16(a0f[mf], b0f[nf], acc[mf][nf], 0, 0, 0);
      }
  }

  const float sc = 1.0f / (256.0f * 2048.0f);   // 2^-19 exact
  const int cbase = bn + wn + (l & 15);
#pragma unroll
  for (int mf = 0; mf < 4; ++mf) {
#pragma unroll
    for (int i = 0; i < 4; ++i) {
      int row = bm + wm + mf * 16 + ((l >> 4) << 2) + i;
#pragma unroll
      for (int nf = 0; nf < 4; ++nf) {
        int col = cbase + nf * 16;
        float v = acc[mf][nf][i] * sc;
        v = v / (1.0f + expf(-v));              // SiLU, precision path
        if (EPI == 0) {
          float t = v * 256.0f;
          f16 h0 = (f16)t;
          O0[(size_t)row * N + col] = h0;
          O1[(size_t)row * N + col] = (f16)(t - (float)h0);
        } else {
          Cf[(size_t)row * N + col] = v;
        }
      }
    }
  }
}

// ---------------------------------------------------------------------------
// bf16 MFMA GEMM, 256x256 tile, BK=64, 8 waves, 8-phase counted-vmcnt schedule
// (verified round 2). See round-2 comments for the schedule/vmcnt proof.
// ---------------------------------------------------------------------------
__device__ __forceinline__ void stage_half(const bf16* __restrict__ src, int Kd,
                                           int rbase, int k0, char* hb8,
                                           int wid, int l) {
#pragma unroll
  for (int j = 0; j < 2; ++j) {
    int Cc = wid * 128 + j * 64 + l;
    int cc = Cc ^ (((Cc >> 3) & 3) << 1);
    gl_lds16(src + (size_t)(rbase + (cc >> 3)) * Kd + k0 + (cc & 7) * 8,
             hb8 + wid * 2048 + j * 1024);
  }
}

__device__ __forceinline__ v8bf ldsfrag(const char* base, int row, int kb) {
  int p = row * 128 + kb;
  p ^= ((p >> 7) & 3) << 5;
  return *(const v8bf*)(base + p);
}

__device__ __forceinline__ void rd_a(v8bf (&af)[2][4], const char* ab, int mh, int l) {
  const int rb = mh * 64 + (l & 15);
  const int kb = (l >> 4) * 16;
#pragma unroll
  for (int ks = 0; ks < 2; ++ks)
#pragma unroll
    for (int mf = 0; mf < 4; ++mf)
      af[ks][mf] = ldsfrag(ab, rb + mf * 16, ks * 64 + kb);
}

__device__ __forceinline__ void rd_b(v8bf (&bfr)[2][2], const char* bbp, int nh, int wl, int l) {
  const int rb = wl + nh * 32 + (l & 15);
  const int kb = (l >> 4) * 16;
#pragma unroll
  for (int ks = 0; ks < 2; ++ks)
#pragma unroll
    for (int nf = 0; nf < 2; ++nf)
      bfr[ks][nf] = ldsfrag(bbp, rb + nf * 16, ks * 64 + kb);
}

__device__ __forceinline__ void qmfma(v4f (&q)[4][2], const v8bf (&af)[2][4],
                                      const v8bf (&bfr)[2][2]) {
  __builtin_amdgcn_s_setprio(1);
#pragma unroll
  for (int ks = 0; ks < 2; ++ks)
#pragma unroll
    for (int mf = 0; mf < 4; ++mf)
#pragma unroll
      for (int nf = 0; nf < 2; ++nf)
        q[mf][nf] = __builtin_amdgcn_mfma_f32_16x16x32_bf16(af[ks][mf], bfr[ks][nf],
                                                            q[mf][nf], 0, 0, 0);
  __builtin_amdgcn_s_setprio(0);
}

#define PHASE_BAR() do { __builtin_amdgcn_s_barrier(); __builtin_amdgcn_sched_barrier(0); } while (0)

template <int EPI>
__global__ __launch_bounds__(512, 2) void bgemm8(
    const bf16* __restrict__ A, const bf16* __restrict__ Wt,
    const float* __restrict__ bias, void* __restrict__ Cv, int N, int Kd) {
  __shared__ __align__(16) char smem[131072];
  const int tid = threadIdx.x;
  const int wid = tid >> 6, l = tid & 63;
  int bm, bn;
  xcd_swizzle256(bm, bn);
  const int ha = wid >> 2;            // this wave's A half
  const int hbv = (wid & 3) >> 1;     // this wave's B half
  const int wl = (wid & 1) * 64;      // B row base within half
  const int NT = Kd >> 6;             // K-tiles (BK=64), NT >= 2

  v4f acc[2][2][4][2];
  v4f z4 = {0.0f, 0.0f, 0.0f, 0.0f};
#pragma unroll
  for (int a = 0; a < 2; ++a)
#pragma unroll
    for (int b = 0; b < 2; ++b)
#pragma unroll
      for (int c = 0; c < 4; ++c)
#pragma unroll
        for (int d = 0; d < 2; ++d) acc[a][b][c][d] = z4;

  // prologue: tile0 {A0,A1,B0,B1}, tile1 {A0,A1}; keep 4 in flight (=A(1))
  stage_half(A,  Kd, bm,       0,  smem + 0,     wid, l);
  stage_half(A,  Kd, bm + 128, 0,  smem + 16384, wid, l);
  stage_half(Wt, Kd, bn,       0,  smem + 32768, wid, l);
  stage_half(Wt, Kd, bn + 128, 0,  smem + 49152, wid, l);
  stage_half(A,  Kd, bm,       64, smem + 65536, wid, l);
  stage_half(A,  Kd, bm + 128, 64, smem + 81920, wid, l);
  asm volatile("s_waitcnt vmcnt(4)" ::: "memory");
  PHASE_BAR();

  for (int K = 0; K < NT; ++K) {
    const int cur = K & 1;
    const char* ab = smem + cur * 65536 + ha * 16384;
    const char* bb = smem + cur * 65536 + 32768 + hbv * 16384;
    char* stB = smem + ((K + 1) & 1) * 65536 + 32768;
    char* stA = smem + cur * 65536;
    const int kB = (K + 1 < NT) ? (K + 1) << 6 : 0;   // clamp: dummy keeps vmcnt exact
    const int kA = (K + 2 < NT) ? (K + 2) << 6 : 0;
    v8bf a0[2][4], a1[2][4], b0[2][2], b1[2][2];

    // q0: Q(0,0) — read a0,b0; stage B-half0(K+1)
    rd_a(a0, ab, 0, l);
    rd_b(b0, bb, 0, wl, l);
    stage_half(Wt, Kd, bn, kB, stB, wid, l);
    PHASE_BAR();
    qmfma(acc[0][0], a0, b0);
    PHASE_BAR();
    // q1: Q(0,1) — read b1; stage B-half1(K+1); a0 dies here
    rd_b(b1, bb, 1, wl, l);
    stage_half(Wt, Kd, bn + 128, kB, stB + 16384, wid, l);
    PHASE_BAR();
    qmfma(acc[0][1], a0, b1);
    PHASE_BAR();
    // q2: Q(1,0) — read a1 (last A read of this tile); b0 dies here
    rd_a(a1, ab, 1, l);
    PHASE_BAR();
    qmfma(acc[1][0], a1, b0);
    PHASE_BAR();
    // q3: Q(1,1) — reg-only compute; stage A(K+2) over this tile's A region
    stage_half(A, Kd, bm, kA, stA, wid, l);
    stage_half(A, Kd, bm + 128, kA, stA + 16384, wid, l);
    PHASE_BAR();
    qmfma(acc[1][1], a1, b1);
    asm volatile("s_waitcnt vmcnt(4)" ::: "memory");
    PHASE_BAR();
  }
  asm volatile("s_waitcnt vmcnt(0)" ::: "memory");

  const int r0 = bm + ha * 128 + ((l >> 4) << 2);
  const int c0 = bn + (wid & 3) * 64 + (l & 15);
  float bb4[2][2];
  if (EPI != 0) {
#pragma unroll
    for (int nh = 0; nh < 2; ++nh)
#pragma unroll
      for (int nf = 0; nf < 2; ++nf) bb4[nh][nf] = bias[c0 + nh * 32 + nf * 16];
  }
#pragma unroll
  for (int mh = 0; mh < 2; ++mh)
#pragma unroll
    for (int mf = 0; mf < 4; ++mf)
#pragma unroll
      for (int i = 0; i < 4; ++i) {
        const int row = r0 + mh * 64 + mf * 16 + i;
#pragma unroll
        for (int nh = 0; nh < 2; ++nh)
#pragma unroll
          for (int nf = 0; nf < 2; ++nf) {
            const int col = c0 + nh * 32 + nf * 16;
            float v = acc[mh][nh][mf][nf][i];
            if (EPI == 0) {
              v = v / (1.0f + __expf(-v));
              ((bf16*)Cv)[(size_t)row * N + col] = (bf16)v;
            } else if (EPI == 1) {
              v += bb4[nh][nf];
              ((bf16*)Cv)[(size_t)row * N + col] = (bf16)v;
            } else {
              v += bb4[nh][nf];
              ((float*)Cv)[(size_t)row * N + col] = v;
            }
          }
      }
}

// ---------------------------------------------------------------------------
// row layernorm + relu, in place; block per row
// ---------------------------------------------------------------------------
template <int VPT, typename T>
__global__ __launch_bounds__(256) void ln_relu(T* __restrict__ x,
    const float* __restrict__ g, const float* __restrict__ b) {
  const int N = VPT * 256;
  const size_t base = (size_t)blockIdx.x * N;
  const int tid = threadIdx.x, w = tid >> 6, l = tid & 63;
  float v[VPT];
#pragma unroll
  for (int q = 0; q < VPT; ++q) v[q] = (float)x[base + q * 256 + tid];
  float s = 0.0f;
#pragma unroll
  for (int q = 0; q < VPT; ++q) s += v[q];
#pragma unroll
  for (int m = 1; m < 64; m <<= 1) s += __shfl_xor(s, m, 64);
  __shared__ float red[8];
  if (l == 0) red[w] = s;
  __syncthreads();
  float mean = (red[0] + red[1] + red[2] + red[3]) * (1.0f / N);
  float ss = 0.0f;
#pragma unroll
  for (int q = 0; q < VPT; ++q) { float t = v[q] - mean; ss += t * t; }
#pragma unroll
  for (int m = 1; m < 64; m <<= 1) ss += __shfl_xor(ss, m, 64);
  if (l == 0) red[4 + w] = ss;
  __syncthreads();
  float var = (red[4] + red[5] + red[6] + red[7]) * (1.0f / N);
  float rs = 1.0f / sqrtf(var + 1e-5f);
#pragma unroll
  for (int q = 0; q < VPT; ++q) {
    int j = q * 256 + tid;
    float y = (v[q] - mean) * rs * g[j] + b[j];
    x[base + j] = (T)fmaxf(y, 0.0f);
  }
}

// ---------------------------------------------------------------------------
// launch
// ---------------------------------------------------------------------------
extern "C" void kernel_launch(void* const* d_in, const int* in_sizes, int n_in,
                              void* d_out, int out_size, void* d_ws, size_t ws_size,
                              hipStream_t stream) {
  (void)in_sizes; (void)n_in; (void)out_size; (void)ws_size;
  const float* semI  = (const float*)d_in[0];
  const float* colI  = (const float*)d_in[1];
  const float* gw1   = (const float*)d_in[2];
  const float* gb1   = (const float*)d_in[3];
  const float* glng  = (const float*)d_in[4];
  const float* glnb  = (const float*)d_in[5];
  const float* gw2   = (const float*)d_in[6];
  const float* gb2   = (const float*)d_in[7];
  const float* fg    = (const float*)d_in[8];
  const float* fb    = (const float*)d_in[9];
  const float* ew1   = (const float*)d_in[10];
  const float* ew2   = (const float*)d_in[11];
  const float* ew3   = (const float*)d_in[12];
  const float* ew4   = (const float*)d_in[13];
  const float* dw1   = (const float*)d_in[14];
  const float* dw2   = (const float*)d_in[15];
  const float* dw3   = (const float*)d_in[16];
  const float* sw1   = (const float*)d_in[17];
  const float* sb1   = (const float*)d_in[18];
  const float* slng  = (const float*)d_in[19];
  const float* slnb  = (const float*)d_in[20];
  const float* sw2   = (const float*)d_in[21];
  const float* sb2   = (const float*)d_in[22];
  const float* cw1   = (const float*)d_in[23];
  const float* cb1   = (const float*)d_in[24];
  const float* clng  = (const float*)d_in[25];
  const float* clnb  = (const float*)d_in[26];
  const float* cw2   = (const float*)d_in[27];
  const float* cb2   = (const float*)d_in[28];
  const float* cbk   = (const float*)d_in[29];

  float* out = (float*)d_out;
  char* ws = (char*)d_ws;

  // output offsets (floats)
  const size_t OUT_SEM = 0, OUT_COL = 50331648, OUT_ZQ = 54525952,
               OUT_CODES = 58720256, OUT_CB = 58916864, OUT_GATE = 58916866;

  // ws layout (bytes)
  bf16* dec1t = (bf16*)(ws + 0);
  bf16* dec2t = (bf16*)(ws + 16384);
  bf16* dec3t = (bf16*)(ws + 81920);
  bf16* sem1t = (bf16*)(ws + 344064);
  bf16* sem2t = (bf16*)(ws + 1916928);
  bf16* col1t = (bf16*)(ws + 4276224);
  float* cbT  = (float*)(ws + 4538368);
  float* nhn  = (float*)(ws + 4734976);
  f16* e1w0   = (f16*)(ws + 4739072);
  f16* e1w1   = (f16*)(ws + 5591040);
  f16* e2w0   = (f16*)(ws + 6443008);
  f16* e2w1   = (f16*)(ws + 6705152);
  f16* e3w0   = (f16*)(ws + 6967296);
  f16* e3w1   = (f16*)(ws + 7032832);
  const size_t WS_A = 8388608, WS_B = 226492416;
  // fused planes occupy exactly the old fp32 fused footprint (218103808 B)
  f16* fA0 = (f16*)(ws + WS_A);
  f16* fA1 = (f16*)(ws + WS_A + 109051904);
  float* scores = (float*)(ws + WS_A);            // reuses fused after E1
  bf16*  semh   = (bf16*)(ws + WS_A);             // reuses scores after RQ
  float* den = (float*)(ws + WS_B);               // pre-E1 temp
  float* hn  = (float*)(ws + WS_B + 16777216);    // pre-E1 temp
  // h1/h2 planes in the old fp32 footprints
  f16* h1a = (f16*)(ws + WS_B);
  f16* h1b = (f16*)(ws + WS_B + 67108864);
  f16* h2a = (f16*)(ws + 360710144);
  f16* h2b = (f16*)(ws + 360710144 + 33554432);
  float* h3  = (float*)(ws + 427819008);
  float* rn  = (float*)(ws + 461373440);
  bf16* zqb  = (bf16*)(ws + WS_B);
  bf16* d1b  = (bf16*)(ws + WS_B + 8388608);
  bf16* d2b  = (bf16*)(ws + WS_B + 25165824);
  bf16* sb   = (bf16*)(ws + WS_B + 58720256);
  float* colh = (float*)(ws + WS_B + 125829120);

  // zero the two loss scalars (d_out is poisoned each launch)
  hipMemsetAsync(out + OUT_CB, 0, 2 * sizeof(float), stream);

  // weight prep
  wconv_t<<<(64 * 128 + 255) / 256, 256, 0, stream>>>(dw1, dec1t, 64, 128);
  wconv_t<<<(128 * 256 + 255) / 256, 256, 0, stream>>>(dw2, dec2t, 128, 256);
  wconv_t<<<(256 * 512 + 255) / 256, 256, 0, stream>>>(dw3, dec3t, 256, 512);
  wconv_t<<<(512 * 1536 + 255) / 256, 256, 0, stream>>>(sw1, sem1t, 512, 1536);
  wconv_t<<<(1536 * 768 + 255) / 256, 256, 0, stream>>>(sw2, sem2t, 1536, 768);
  wconv_t<<<(512 * 256 + 255) / 256, 256, 0, stream>>>(cw1, col1t, 512, 256);
  wsplit_t<<<(832 * 512 + 255) / 256, 256, 0, stream>>>(ew1, e1w0, e1w1, 832, 512);
  wsplit_t<<<(512 * 256 + 255) / 256, 256, 0, stream>>>(ew2, e2w0, e2w1, 512, 256);
  wsplit_t<<<(256 * 128 + 255) / 256, 256, 0, stream>>>(ew3, e3w0, e3w1, 256, 128);
  cbt_k<<<192, 256, 0, stream>>>(cbk, cbT);
  nhn_k<<<3, 256, 0, stream>>>(cbk, nhn);

  // gate network (fp32)
  sgemm128<2><<<dim3(1, 512), 256, 0, stream>>>(colI, gw1, gb1, glng, glnb, hn, 128, 64);
  sgemm64<2><<<512, 256, 0, stream>>>(hn, gw2, gb2, colI, out + OUT_GATE, den, 128);
  fuse_ln<<<4096, 256, 0, stream>>>(semI, den, fg, fb, fA0, fA1);

  // encoder: pre-split fp16 planes, m97 structure, no in-loop VALU split
  hgemmp<0><<<dim3(4, 512), 256, 0, stream>>>(fA0, fA1, e1w0, e1w1, h1a, h1b, nullptr, 512, 832);
  hgemmp<0><<<dim3(2, 512), 256, 0, stream>>>(h1a, h1b, e2w0, e2w1, h2a, h2b, nullptr, 256, 512);
  hgemmp<1><<<dim3(1, 512), 256, 0, stream>>>(h2a, h2b, e3w0, e3w1, nullptr, nullptr, h3, 128, 256);
  sgemm64<0><<<512, 256, 0, stream>>>(h3, ew4, nullptr, nullptr, rn, nullptr, 128);

  // residual quantization (fp32 scores as GEMM + argmax/update)
  sgemm128<1><<<dim3(2, 512), 256, 0, stream>>>(rn, cbT + 0 * 16384, nhn + 0, nullptr, nullptr, scores, 256, 64);
  argupd<0><<<1024, 256, 0, stream>>>(scores, cbk + 0 * 16384, rn, out + OUT_ZQ, out + OUT_CODES, out + OUT_CB, zqb);
  sgemm128<1><<<dim3(2, 512), 256, 0, stream>>>(rn, cbT + 1 * 16384, nhn + 256, nullptr, nullptr, scores, 256, 64);
  argupd<1><<<1024, 256, 0, stream>>>(scores, cbk + 1 * 16384, rn, out + OUT_ZQ, out + OUT_CODES, out + OUT_CB, zqb);
  sgemm128<1><<<dim3(2, 512), 256, 0, stream>>>(rn, cbT + 2 * 16384, nhn + 512, nullptr, nullptr, scores, 256, 64);
  argupd<2><<<1024, 256, 0, stream>>>(scores, cbk + 2 * 16384, rn, out + OUT_ZQ, out + OUT_CODES, out + OUT_CB, zqb);

  // decoder + heads (bf16 MFMA; big GEMMs on the 256^2 8-phase structure)
  bgemm<0><<<dim3(1, 512), 256, 0, stream>>>(zqb, dec1t, nullptr, d1b, 128, 64);
  bgemm8<0><<<dim3(1, 256), 512, 0, stream>>>(d1b, dec2t, nullptr, d2b, 256, 128);
  bgemm8<0><<<dim3(2, 256), 512, 0, stream>>>(d2b, dec3t, nullptr, sb, 512, 256);
  bgemm8<1><<<dim3(6, 256), 512, 0, stream>>>(sb, sem1t, sb1, semh, 1536, 512);
  ln_relu<6, bf16><<<65536, 256, 0, stream>>>(semh, slng, slnb);
  bgemm8<2><<<dim3(3, 256), 512, 0, stream>>>(semh, sem2t, sb2, out + OUT_SEM, 768, 1536);
  bgemm8<2><<<dim3(1, 256), 512, 0, stream>>>(sb, col1t, cb1, colh, 256, 512);
  ln_relu<1, float><<<65536, 256, 0, stream>>>(colh, clng, clnb);
  sgemm64<1><<<512, 256, 0, stream>>>(colh, cw2, cb2, nullptr, out + OUT_COL, nullptr, 256);
}

// Round 6
// 1790.487 us; speedup vs baseline: 1.1714x; 1.0684x over previous
//
#include <hip/hip_runtime.h>
#include <hip/hip_bf16.h>
#include <math.h>

typedef __bf16 bf16;
typedef __attribute__((ext_vector_type(8))) __bf16 v8bf;
typedef __attribute__((ext_vector_type(4))) float v4f;
typedef _Float16 f16;
typedef __attribute__((ext_vector_type(8))) _Float16 v8h;
typedef __attribute__((ext_vector_type(4))) _Float16 v4h;

// XCD-ownership block swizzle (128 tiles). Requires gridDim.y % 8 == 0.
__device__ __forceinline__ void xcd_swizzle(int& bm, int& bn) {
  const int nx = gridDim.x;
  const int id = blockIdx.y * nx + blockIdx.x;
  const int slot = id >> 3;
  const int row_in = slot / nx;
  const int bmi = (id & 7) * (gridDim.y >> 3) + row_in;
  const int bni = slot - row_in * nx;
  bm = bmi << 7; bn = bni << 7;
}

// same, 256x256 tiles
__device__ __forceinline__ void xcd_swizzle256(int& bm, int& bn) {
  const int nx = gridDim.x;
  const int id = blockIdx.y * nx + blockIdx.x;
  const int slot = id >> 3;
  const int row_in = slot / nx;
  const int bmi = (id & 7) * (gridDim.y >> 3) + row_in;
  const int bni = slot - row_in * nx;
  bm = bmi << 8; bn = bni << 8;
}

// ---------------------------------------------------------------------------
// small prep kernels
// ---------------------------------------------------------------------------
__global__ void wconv_t(const float* __restrict__ W, bf16* __restrict__ Wt, int Kd, int Nd) {
  int e = blockIdx.x * 256 + threadIdx.x;
  if (e < Kd * Nd) {
    int k = e / Nd, n = e - k * Nd;
    Wt[n * Kd + k] = (bf16)W[e];   // store transposed [N][K] for gemm_bt
  }
}

// fp32 -> 2-plane fp16 split, transposed, pre-scaled by 2048
__global__ void wsplit_t(const float* __restrict__ W, f16* __restrict__ W0,
                         f16* __restrict__ W1, int Kd, int Nd) {
  int e = blockIdx.x * 256 + threadIdx.x;
  if (e < Kd * Nd) {
    int k = e / Nd, n = e - k * Nd;
    float v = W[e] * 2048.0f;
    f16 h0 = (f16)v;
    f16 h1 = (f16)(v - (float)h0);
    W0[n * Kd + k] = h0;
    W1[n * Kd + k] = h1;
  }
}

__global__ void cbt_k(const float* __restrict__ cb, float* __restrict__ cbT) {
  int e = blockIdx.x * 256 + threadIdx.x;   // 3*256*64 total
  if (e < 3 * 256 * 64) {
    int l = e >> 14, rem = e & 16383;
    int c = rem >> 6, d = rem & 63;
    cbT[l * 16384 + d * 256 + c] = cb[e];   // [l][d][c]
  }
}

__global__ void nhn_k(const float* __restrict__ cb, float* __restrict__ nhn) {
  int l = blockIdx.x, c = threadIdx.x;      // grid 3 x 256
  const float* p = cb + l * 16384 + c * 64;
  double s = 0.0;
  for (int d = 0; d < 64; ++d) { double v = (double)p[d]; s += v * v; }
  nhn[l * 256 + c] = (float)(-0.5 * s);
}

// ---------------------------------------------------------------------------
// fp32 GEMM, 128x128 tile, BK=32, 8x8 per thread.
// EPI: 0 = SiLU->f32, 1 = +bias->f32, 2 = +bias, LN(128), ReLU -> f32 (needs gridDim.x==1,N==128)
// ---------------------------------------------------------------------------
template <int EPI>
__global__ __launch_bounds__(256, 2) void sgemm128(
    const float* __restrict__ A, const float* __restrict__ W,
    const float* __restrict__ bias, const float* __restrict__ lng,
    const float* __restrict__ lnb, float* __restrict__ C, int N, int Kd) {
  __shared__ float As[32][132];   // [k][m], padded
  __shared__ float Bs[32][128];   // [k][n]
  const int tid = threadIdx.x;
  const int w = tid >> 6, l = tid & 63;
  int tx, ty;
  if (EPI == 2) { tx = tid & 15; ty = tid >> 4; }
  else { tx = ((w & 1) << 3) | (l & 7); ty = ((w >> 1) << 3) | (l >> 3); }
  int bm, bn;
  xcd_swizzle(bm, bn);

  float acc[8][8];
#pragma unroll
  for (int i = 0; i < 8; ++i)
#pragma unroll
    for (int j = 0; j < 8; ++j) acc[i][j] = 0.0f;

  for (int k0 = 0; k0 < Kd; k0 += 32) {
    __syncthreads();
#pragma unroll
    for (int jj = 0; jj < 4; ++jj) {
      int p = tid + 256 * jj;
      int arow = p >> 3, aks = (p & 7) << 2;
      float4 v = *(const float4*)(A + (size_t)(bm + arow) * Kd + k0 + aks);
      As[aks][arow] = v.x; As[aks + 1][arow] = v.y;
      As[aks + 2][arow] = v.z; As[aks + 3][arow] = v.w;
      int bk = p >> 5, bns = (p & 31) << 2;
      float4 u = *(const float4*)(W + (size_t)(k0 + bk) * N + bn + bns);
      *(float4*)(&Bs[bk][bns]) = u;
    }
    __syncthreads();
    float cacc[8][8];
#pragma unroll
    for (int i = 0; i < 8; ++i)
#pragma unroll
      for (int j = 0; j < 8; ++j) cacc[i][j] = 0.0f;
#pragma unroll 4
    for (int kk = 0; kk < 32; ++kk) {
      float a[8], b[8];
#pragma unroll
      for (int i = 0; i < 8; ++i) a[i] = As[kk][ty * 8 + i];
#pragma unroll
      for (int j = 0; j < 8; ++j) b[j] = Bs[kk][tx * 8 + j];
#pragma unroll
      for (int i = 0; i < 8; ++i)
#pragma unroll
        for (int j = 0; j < 8; ++j) cacc[i][j] = fmaf(a[i], b[j], cacc[i][j]);
    }
#pragma unroll
    for (int i = 0; i < 8; ++i)
#pragma unroll
      for (int j = 0; j < 8; ++j) acc[i][j] += cacc[i][j];
  }

  const int colb = bn + tx * 8;
  if (EPI == 0) {
#pragma unroll
    for (int i = 0; i < 8; ++i) {
      int row = bm + ty * 8 + i;
      float o[8];
#pragma unroll
      for (int j = 0; j < 8; ++j) { float v = acc[i][j]; o[j] = v / (1.0f + expf(-v)); }
      *(float4*)(C + (size_t)row * N + colb) = make_float4(o[0], o[1], o[2], o[3]);
      *(float4*)(C + (size_t)row * N + colb + 4) = make_float4(o[4], o[5], o[6], o[7]);
    }
  } else if (EPI == 1) {
    float bb[8];
#pragma unroll
    for (int j = 0; j < 8; ++j) bb[j] = bias[colb + j];
#pragma unroll
    for (int i = 0; i < 8; ++i) {
      int row = bm + ty * 8 + i;
      float o[8];
#pragma unroll
      for (int j = 0; j < 8; ++j) o[j] = acc[i][j] + bb[j];
      *(float4*)(C + (size_t)row * N + colb) = make_float4(o[0], o[1], o[2], o[3]);
      *(float4*)(C + (size_t)row * N + colb + 4) = make_float4(o[4], o[5], o[6], o[7]);
    }
  } else {
    float bb[8], lg[8], lb[8];
#pragma unroll
    for (int j = 0; j < 8; ++j) { bb[j] = bias[colb + j]; lg[j] = lng[colb + j]; lb[j] = lnb[colb + j]; }
#pragma unroll
    for (int i = 0; i < 8; ++i) {
      int row = bm + ty * 8 + i;
      float v[8]; float s = 0.0f;
#pragma unroll
      for (int j = 0; j < 8; ++j) { v[j] = acc[i][j] + bb[j]; s += v[j]; }
      s += __shfl_xor(s, 1); s += __shfl_xor(s, 2); s += __shfl_xor(s, 4); s += __shfl_xor(s, 8);
      float mean = s * (1.0f / 128.0f);
      float ss = 0.0f;
#pragma unroll
      for (int j = 0; j < 8; ++j) { float t = v[j] - mean; ss += t * t; }
      ss += __shfl_xor(ss, 1); ss += __shfl_xor(ss, 2); ss += __shfl_xor(ss, 4); ss += __shfl_xor(ss, 8);
      float rs = 1.0f / sqrtf(ss * (1.0f / 128.0f) + 1e-5f);
      float o[8];
#pragma unroll
      for (int j = 0; j < 8; ++j) o[j] = fmaxf((v[j] - mean) * rs * lg[j] + lb[j], 0.0f);
      *(float4*)(C + (size_t)row * N + colb) = make_float4(o[0], o[1], o[2], o[3]);
      *(float4*)(C + (size_t)row * N + colb + 4) = make_float4(o[4], o[5], o[6], o[7]);
    }
  }
}

// ---------------------------------------------------------------------------
// fp32 GEMM, 128x64 tile (N fixed 64), BK=32, 8x4 per thread.
// EPI: 0 = l2norm row -> C, 1 = +bias -> C, 2 = gate (sigmoid->C, gate*aux->C2)
// ---------------------------------------------------------------------------
template <int EPI>
__global__ __launch_bounds__(256, 2) void sgemm64(
    const float* __restrict__ A, const float* __restrict__ W,
    const float* __restrict__ bias, const float* __restrict__ aux,
    float* __restrict__ C, float* __restrict__ C2, int Kd) {
  __shared__ float As[32][132];
  __shared__ float Bs[32][64];
  const int tid = threadIdx.x;
  const int tx = tid & 15, ty = tid >> 4;
  const int bm = blockIdx.x << 7;

  float acc[8][4];
#pragma unroll
  for (int i = 0; i < 8; ++i)
#pragma unroll
    for (int j = 0; j < 4; ++j) acc[i][j] = 0.0f;

  for (int k0 = 0; k0 < Kd; k0 += 32) {
    __syncthreads();
#pragma unroll
    for (int jj = 0; jj < 4; ++jj) {
      int p = tid + 256 * jj;
      int arow = p >> 3, aks = (p & 7) << 2;
      float4 v = *(const float4*)(A + (size_t)(bm + arow) * Kd + k0 + aks);
      As[aks][arow] = v.x; As[aks + 1][arow] = v.y;
      As[aks + 2][arow] = v.z; As[aks + 3][arow] = v.w;
    }
#pragma unroll
    for (int jj = 0; jj < 2; ++jj) {
      int p = tid + 256 * jj;
      int bk = p >> 4, bns = (p & 15) << 2;
      float4 u = *(const float4*)(W + (size_t)(k0 + bk) * 64 + bns);
      *(float4*)(&Bs[bk][bns]) = u;
    }
    __syncthreads();
    float cacc[8][4];
#pragma unroll
    for (int i = 0; i < 8; ++i)
#pragma unroll
      for (int j = 0; j < 4; ++j) cacc[i][j] = 0.0f;
#pragma unroll 4
    for (int kk = 0; kk < 32; ++kk) {
      float a[8], b[4];
#pragma unroll
      for (int i = 0; i < 8; ++i) a[i] = As[kk][ty * 8 + i];
#pragma unroll
      for (int j = 0; j < 4; ++j) b[j] = Bs[kk][tx * 4 + j];
#pragma unroll
      for (int i = 0; i < 8; ++i)
#pragma unroll
        for (int j = 0; j < 4; ++j) cacc[i][j] = fmaf(a[i], b[j], cacc[i][j]);
    }
#pragma unroll
    for (int i = 0; i < 8; ++i)
#pragma unroll
      for (int j = 0; j < 4; ++j) acc[i][j] += cacc[i][j];
  }

  const int colb = tx * 4;
  if (EPI == 0) {           // l2norm(z) -> rn
#pragma unroll
    for (int i = 0; i < 8; ++i) {
      int row = bm + ty * 8 + i;
      float ss = 0.0f;
#pragma unroll
      for (int j = 0; j < 4; ++j) ss += acc[i][j] * acc[i][j];
      ss += __shfl_xor(ss, 1); ss += __shfl_xor(ss, 2); ss += __shfl_xor(ss, 4); ss += __shfl_xor(ss, 8);
      float nrm = fmaxf(sqrtf(ss), 1e-12f);
      *(float4*)(C + (size_t)row * 64 + colb) =
          make_float4(acc[i][0] / nrm, acc[i][1] / nrm, acc[i][2] / nrm, acc[i][3] / nrm);
    }
  } else if (EPI == 1) {
    float bb[4];
#pragma unroll
    for (int j = 0; j < 4; ++j) bb[j] = bias[colb + j];
#pragma unroll
    for (int i = 0; i < 8; ++i) {
      int row = bm + ty * 8 + i;
      *(float4*)(C + (size_t)row * 64 + colb) =
          make_float4(acc[i][0] + bb[0], acc[i][1] + bb[1], acc[i][2] + bb[2], acc[i][3] + bb[3]);
    }
  } else {                  // gate: sigmoid -> C (gate_values), gate*collab -> C2 (denoised)
    float bb[4];
#pragma unroll
    for (int j = 0; j < 4; ++j) bb[j] = bias[colb + j];
#pragma unroll
    for (int i = 0; i < 8; ++i) {
      int row = bm + ty * 8 + i;
      float4 av = *(const float4*)(aux + (size_t)row * 64 + colb);
      float g[4];
#pragma unroll
      for (int j = 0; j < 4; ++j) g[j] = 1.0f / (1.0f + expf(-(acc[i][j] + bb[j])));
      *(float4*)(C + (size_t)row * 64 + colb) = make_float4(g[0], g[1], g[2], g[3]);
      *(float4*)(C2 + (size_t)row * 64 + colb) =
          make_float4(g[0] * av.x, g[1] * av.y, g[2] * av.z, g[3] * av.w);
    }
  }
}

// ---------------------------------------------------------------------------
// fusion layernorm over 832; wave per row. Emits the 2-plane f16 split of the
// normalized row (x256 scale). (verified round 3: bitwise-equal)
// ---------------------------------------------------------------------------
__global__ __launch_bounds__(256) void fuse_ln(
    const float* __restrict__ sem, const float* __restrict__ den,
    const float* __restrict__ fg, const float* __restrict__ fb,
    f16* __restrict__ fA0, f16* __restrict__ fA1) {
  const int w = threadIdx.x >> 6, l = threadIdx.x & 63;
  float fgv[13], fbv[13];
#pragma unroll
  for (int q = 0; q < 12; ++q) { fgv[q] = fg[q * 64 + l]; fbv[q] = fb[q * 64 + l]; }
  fgv[12] = fg[768 + l]; fbv[12] = fb[768 + l];
  for (int it = 0; it < 4; ++it) {
    int r = (blockIdx.x * 4 + w) * 4 + it;
    float sv[12];
#pragma unroll
    for (int q = 0; q < 12; ++q) sv[q] = sem[(size_t)r * 768 + q * 64 + l];
    float dv = den[(size_t)r * 64 + l];
    float s = dv;
#pragma unroll
    for (int q = 0; q < 12; ++q) s += sv[q];
#pragma unroll
    for (int m = 1; m < 64; m <<= 1) s += __shfl_xor(s, m, 64);
    float mean = s * (1.0f / 832.0f);
    float t0 = dv - mean;
    float ss = t0 * t0;
#pragma unroll
    for (int q = 0; q < 12; ++q) { float t = sv[q] - mean; ss += t * t; }
#pragma unroll
    for (int m = 1; m < 64; m <<= 1) ss += __shfl_xor(ss, m, 64);
    float sc = 1.0f / sqrtf(ss * (1.0f / 832.0f) + 1e-5f);
#pragma unroll
    for (int q = 0; q < 13; ++q) {
      float y = (q < 12) ? ((sv[q] - mean) * sc * fgv[q] + fbv[q])
                         : (t0 * sc * fgv[12] + fbv[12]);
      float t = y * 256.0f;
      f16 h0 = (f16)t;
      size_t idx = (size_t)r * 832 + q * 64 + l;
      fA0[idx] = h0;
      fA1[idx] = (f16)(t - (float)h0);
    }
  }
}

// ---------------------------------------------------------------------------
// async global->LDS helper
// ---------------------------------------------------------------------------
typedef __attribute__((address_space(3))) void lds_void_t;
typedef __attribute__((address_space(1))) const void gbl_void_t;
__device__ __forceinline__ void gl_lds16(const void* g, void* l) {
  __builtin_amdgcn_global_load_lds((gbl_void_t*)g, (lds_void_t*)l, 16, 0, 0);
}

// ---------------------------------------------------------------------------
// FUSED residual quantization: all 3 layers in one kernel.
// Block = 256 threads (4 waves), 64 consecutive rows; rn rows live in LDS
// across layers, zq accumulators in registers, codebook layer staged in LDS.
// STAGING NOTE (round-5 fix): global_load_lds requires a WAVE-UNIFORM LDS
// base (HW writes base + lane*16; per-lane LDS pointers are undefined —
// m104/m108). Chunk base cb0 = w*64 + j*256 is wave-uniform; the per-lane
// global source is src + cb0*4 + l*4 floats. Same bytes as before, now in
// the exact shape of the verified stage_* helpers.
// Numerics replicate the old sgemm128<1>+argupd chain bitwise:
//  - score = (fma-chain kk 0..31) + (fma-chain kk 32..63) + nhn[c]
//  - argmax: strict-greater ascending scan + (max, min-index) lattice —
//    order-independent, identical winner to the old reduction.
//  - update math is argupd's verbatim; same 16-row lacc partial sets.
// Eliminates the 67MB scores buffer (3x write + 3x read) and 5 launches.
// ---------------------------------------------------------------------------
__global__ __launch_bounds__(256, 1) void rq_all(
    const float* __restrict__ rn_in, const float* __restrict__ cbT,
    const float* __restrict__ nhn, const float* __restrict__ cbk,
    float* __restrict__ zq, float* __restrict__ codes,
    float* __restrict__ loss, bf16* __restrict__ zqb) {
  __shared__ __align__(16) float Al[64 * 64];     // [row][d]
  __shared__ __align__(16) float Bl[64 * 256];    // [d][code]
  __shared__ int rowbi[64];
  const int tid = threadIdx.x;
  const int w = tid >> 6, l = tid & 63;
  const int tx = tid & 31, ty = tid >> 5;         // GEMM map: 8 strided codes, 8 rows
  const int r0 = blockIdx.x << 6;

  // stage rn rows -> Al: wave-uniform LDS base, per-lane global source
#pragma unroll
  for (int j = 0; j < 4; ++j) {
    const int cb0 = (w << 6) + (j << 8);          // w*64 + j*256 (uniform)
    gl_lds16(rn_in + (size_t)r0 * 64 + cb0 * 4 + l * 4, (char*)Al + cb0 * 16);
  }

  float zqa[16];
#pragma unroll
  for (int i = 0; i < 16; ++i) zqa[i] = 0.0f;

  for (int L = 0; L < 3; ++L) {
    __syncthreads();   // prev layer's reads of Bl/Al done; drains A-stage at L=0
#pragma unroll
    for (int j = 0; j < 16; ++j) {
      const int cb0 = (w << 6) + (j << 8);        // uniform per wave
      gl_lds16(cbT + L * 16384 + cb0 * 4 + l * 4, (char*)Bl + cb0 * 16);
    }
    // nhn for this thread's 8 strided codes: c = 2*tx + 64*j (+1)
    float nh[8];
#pragma unroll
    for (int j = 0; j < 4; ++j) {
      float2 n2 = *(const float2*)(nhn + L * 256 + j * 64 + tx * 2);
      nh[j * 2] = n2.x; nh[j * 2 + 1] = n2.y;
    }
    __syncthreads();   // staging complete (compiler drains vmcnt before barrier)

    // ---- score GEMM: rows ty*8+i, codes 2tx+64j(+1); two kk-ascending chains
    float s0[8][8], s1[8][8];
#pragma unroll
    for (int i = 0; i < 8; ++i)
#pragma unroll
      for (int j = 0; j < 8; ++j) { s0[i][j] = 0.0f; s1[i][j] = 0.0f; }

#define RQ_CHUNK(S, KB)                                                        \
    for (int k4 = 0; k4 < 32; k4 += 4) {                                       \
      float4 av[8];                                                            \
      _Pragma("unroll")                                                        \
      for (int i = 0; i < 8; ++i)                                              \
        av[i] = *(const float4*)(Al + (ty * 8 + i) * 64 + (KB) + k4);          \
      _Pragma("unroll")                                                        \
      for (int kq = 0; kq < 4; ++kq) {                                         \
        float bv[8];                                                           \
        _Pragma("unroll")                                                      \
        for (int j = 0; j < 4; ++j) {                                          \
          float2 b2 = *(const float2*)(Bl + ((KB) + k4 + kq) * 256 + j * 64 + tx * 2); \
          bv[j * 2] = b2.x; bv[j * 2 + 1] = b2.y;                              \
        }                                                                      \
        _Pragma("unroll")                                                      \
        for (int i = 0; i < 8; ++i) {                                          \
          float a_ = (&av[i].x)[kq];                                           \
          _Pragma("unroll")                                                    \
          for (int j = 0; j < 8; ++j) S[i][j] = fmaf(a_, bv[j], S[i][j]);      \
        }                                                                      \
      }                                                                        \
    }
    RQ_CHUNK(s0, 0)
    RQ_CHUNK(s1, 32)
#undef RQ_CHUNK

    // ---- per-row argmax (codes ascending within thread; lattice across lanes)
#pragma unroll
    for (int i = 0; i < 8; ++i) {
      int r = ty * 8 + i;
      float sc[8];
#pragma unroll
      for (int j = 0; j < 8; ++j) sc[j] = (s0[i][j] + s1[i][j]) + nh[j];
      float bs = sc[0]; int bi = 2 * tx;
#pragma unroll
      for (int j = 1; j < 8; ++j) {
        int cj = (j >> 1) * 64 + 2 * tx + (j & 1);
        if (sc[j] > bs) { bs = sc[j]; bi = cj; }
      }
#pragma unroll
      for (int m = 1; m < 32; m <<= 1) {
        float os = __shfl_xor(bs, m, 64);
        int oi = __shfl_xor(bi, m, 64);
        if (os > bs || (os == bs && oi < bi)) { bs = os; bi = oi; }
      }
      if (tx == 0) {
        rowbi[r] = bi;
        codes[(size_t)(r0 + r) * 3 + L] = (float)bi;
      }
    }
    __syncthreads();   // rowbi visible; all GEMM reads of Al quiesced

    // ---- update phase: wave w owns rows w*16..w*16+15, lane l = element l
    float lacc = 0.0f;
    const float* cbkL = cbk + L * 16384;
#pragma unroll
    for (int it = 0; it < 16; ++it) {
      int r = w * 16 + it;
      float rl = Al[r * 64 + l];
      int bi = rowbi[r];
      float e = cbkL[bi * 64 + l];
      float emr = e - rl;
      float zql = rl + emr;          // straight-through fwd, ref rounding order
      lacc += emr * emr;
      if (L == 0) zqa[it] = zql; else zqa[it] += zql;
      if (L < 2) {
        float rnew = rl - zql;
        float ss = rnew * rnew;
#pragma unroll
        for (int m = 1; m < 64; m <<= 1) ss += __shfl_xor(ss, m, 64);
        float nrm = fmaxf(sqrtf(ss), 1e-12f);
        Al[r * 64 + l] = rnew / nrm;
      } else {
        float tot = zqa[it];
        zq[(size_t)(r0 + r) * 64 + l] = tot;
        zqb[(size_t)(r0 + r) * 64 + l] = (bf16)tot;
      }
    }
#pragma unroll
    for (int m = 1; m < 64; m <<= 1) lacc += __shfl_xor(lacc, m, 64);
    if (l == 0) {
      float v = lacc * (1.0f / 4194304.0f);   // 1/(65536*64), exact pow2
      atomicAdd(loss, v);
      atomicAdd(loss + 1, v);
    }
  }
}

// ---------------------------------------------------------------------------
// bf16 MFMA GEMM (m97 structure): 128x128 tile, BK=32 (kept for N=128 case)
// EPI: 0 = SiLU->bf16, 1 = +bias->bf16, 2 = +bias->f32
// ---------------------------------------------------------------------------
template <int EPI>
__global__ __launch_bounds__(256, 3) void bgemm(
    const bf16* __restrict__ A, const bf16* __restrict__ Wt,
    const float* __restrict__ bias, void* __restrict__ Cv, int N, int Kd) {
  __shared__ __align__(16) bf16 As[128 * 32];
  __shared__ __align__(16) bf16 Bs[128 * 32];
  const int tid = threadIdx.x;
  const int w = tid >> 6, l = tid & 63;
  int bm, bn;
  xcd_swizzle(bm, bn);
  const int wm = (w >> 1) << 6, wn = (w & 1) << 6;

  v4f acc[4][4];
  v4f z4 = {0.0f, 0.0f, 0.0f, 0.0f};
#pragma unroll
  for (int i = 0; i < 4; ++i)
#pragma unroll
    for (int j = 0; j < 4; ++j) acc[i][j] = z4;

  const int srow = (w << 5) + (l >> 2);
  const int skc = (l & 3) << 3;
  const bf16* ga0 = A + (size_t)(bm + srow) * Kd + skc;
  const bf16* gb0 = Wt + (size_t)(bn + srow) * Kd + skc;
  char* la0 = (char*)As + (w << 11);
  char* lb0 = (char*)Bs + (w << 11);

  for (int k0 = 0; k0 < Kd; k0 += 32) {
    __syncthreads();
    gl_lds16(ga0 + k0, la0);
    gl_lds16(ga0 + (size_t)16 * Kd + k0, la0 + 1024);
    gl_lds16(gb0 + k0, lb0);
    gl_lds16(gb0 + (size_t)16 * Kd + k0, lb0 + 1024);
    __syncthreads();
    v8bf af[4], bfr[4];
#pragma unroll
    for (int f = 0; f < 4; ++f) {
      af[f] = *(const v8bf*)(As + (wm + f * 16 + (l & 15)) * 32 + ((l >> 4) << 3));
      bfr[f] = *(const v8bf*)(Bs + (wn + f * 16 + (l & 15)) * 32 + ((l >> 4) << 3));
    }
#pragma unroll
    for (int mf = 0; mf < 4; ++mf)
#pragma unroll
      for (int nf = 0; nf < 4; ++nf)
        acc[mf][nf] = __builtin_amdgcn_mfma_f32_16x16x32_bf16(af[mf], bfr[nf], acc[mf][nf], 0, 0, 0);
  }

  const int cbase = bn + wn + (l & 15);
  float bb[4];
  if (EPI != 0) {
#pragma unroll
    for (int nf = 0; nf < 4; ++nf) bb[nf] = bias[cbase + nf * 16];
  }
#pragma unroll
  for (int mf = 0; mf < 4; ++mf) {
#pragma unroll
    for (int i = 0; i < 4; ++i) {
      int row = bm + wm + mf * 16 + ((l >> 4) << 2) + i;
#pragma unroll
      for (int nf = 0; nf < 4; ++nf) {
        int col = cbase + nf * 16;
        float v = acc[mf][nf][i];
        if (EPI == 0) {
          v = v / (1.0f + __expf(-v));
          ((bf16*)Cv)[(size_t)row * N + col] = (bf16)v;
        } else if (EPI == 1) {
          v += bb[nf];
          ((bf16*)Cv)[(size_t)row * N + col] = (bf16)v;
        } else {
          v += bb[nf];
          ((float*)Cv)[(size_t)row * N + col] = v;
        }
      }
    }
  }
}

// ---------------------------------------------------------------------------
// plane staging + swizzled LDS read (verified round 3: 0 bank conflicts).
// ---------------------------------------------------------------------------
__device__ __forceinline__ void stage_plane(const f16* __restrict__ src, int Kd,
                                            int rbase, int k0, char* base,
                                            int wid, int l) {
#pragma unroll
  for (int j = 0; j < 2; ++j) {
    int Cc = wid * 128 + j * 64 + l;
    int cc = Cc ^ ((Cc >> 3) & 3);
    gl_lds16(src + (size_t)(rbase + (cc >> 2)) * Kd + k0 + (cc & 3) * 8,
             base + wid * 2048 + j * 1024);
  }
}

__device__ __forceinline__ v8h ldsfragh(const char* base, int row, int kb) {
  int p = row * 64 + kb;
  p ^= ((p >> 7) & 3) << 4;
  return *(const v8h*)(base + p);
}

// ---------------------------------------------------------------------------
// f16 2-plane GEMM, 128x128 tile, BK=32, m97 structure (3 blocks/CU), fed by
// pre-split planes via global_load_lds — no VALU split in the K-loop.
// (verified round 4)
// EPI: 0 = SiLU -> 2-plane f16 split (x256); 1 = SiLU -> fp32
// ---------------------------------------------------------------------------
template <int EPI>
__global__ __launch_bounds__(256, 3) void hgemmp(
    const f16* __restrict__ A0, const f16* __restrict__ A1,
    const f16* __restrict__ W0, const f16* __restrict__ W1,
    f16* __restrict__ O0, f16* __restrict__ O1, float* __restrict__ Cf,
    int N, int Kd) {
  __shared__ __align__(16) char smem[32768];   // 4 planes x 8KB: A0,A1,B0,B1
  const int tid = threadIdx.x;
  const int w = tid >> 6, l = tid & 63;
  int bm, bn;
  xcd_swizzle(bm, bn);
  const int wm = (w >> 1) << 6, wn = (w & 1) << 6;
  const int kb = (l >> 4) << 4;   // byte offset within 64B row

  char* pa0 = smem;
  char* pa1 = smem + 8192;
  char* pb0 = smem + 16384;
  char* pb1 = smem + 24576;

  v4f acc[4][4];
  v4f z4 = {0.0f, 0.0f, 0.0f, 0.0f};
#pragma unroll
  for (int i = 0; i < 4; ++i)
#pragma unroll
    for (int j = 0; j < 4; ++j) acc[i][j] = z4;

  for (int k0 = 0; k0 < Kd; k0 += 32) {
    __syncthreads();
    stage_plane(A0, Kd, bm, k0, pa0, w, l);
    stage_plane(A1, Kd, bm, k0, pa1, w, l);
    stage_plane(W0, Kd, bn, k0, pb0, w, l);
    stage_plane(W1, Kd, bn, k0, pb1, w, l);
    __syncthreads();
    v8h a0f[4], a1f[4], b0f[4], b1f[4];
#pragma unroll
    for (int f = 0; f < 4; ++f) {
      a0f[f] = ldsfragh(pa0, wm + f * 16 + (l & 15), kb);
      a1f[f] = ldsfragh(pa1, wm + f * 16 + (l & 15), kb);
      b0f[f] = ldsfragh(pb0, wn + f * 16 + (l & 15), kb);
      b1f[f] = ldsfragh(pb1, wn + f * 16 + (l & 15), kb);
    }
#pragma unroll
    for (int mf = 0; mf < 4; ++mf)
#pragma unroll
      for (int nf = 0; nf < 4; ++nf) {
        acc[mf][nf] = __builtin_amdgcn_mfma_f32_16x16x32_f16(a0f[mf], b1f[nf], acc[mf][nf], 0, 0, 0);
        acc[mf][nf] = __builtin_amdgcn_mfma_f32_16x16x32_f16(a1f[mf], b0f[nf], acc[mf][nf], 0, 0, 0);
        acc[mf][nf] = __builtin_amdgcn_mfma_f32_16x16x32_f16(a0f[mf], b0f[nf], acc[mf][nf], 0, 0, 0);
      }
  }

  const float sc = 1.0f / (256.0f * 2048.0f);   // 2^-19 exact
  const int cbase = bn + wn + (l & 15);
#pragma unroll
  for (int mf = 0; mf < 4; ++mf) {
#pragma unroll
    for (int i = 0; i < 4; ++i) {
      int row = bm + wm + mf * 16 + ((l >> 4) << 2) + i;
#pragma unroll
      for (int nf = 0; nf < 4; ++nf) {
        int col = cbase + nf * 16;
        float v = acc[mf][nf][i] * sc;
        v = v / (1.0f + expf(-v));              // SiLU, precision path
        if (EPI == 0) {
          float t = v * 256.0f;
          f16 h0 = (f16)t;
          O0[(size_t)row * N + col] = h0;
          O1[(size_t)row * N + col] = (f16)(t - (float)h0);
        } else {
          Cf[(size_t)row * N + col] = v;
        }
      }
    }
  }
}

// ---------------------------------------------------------------------------
// bf16 MFMA GEMM, 256x256 tile, BK=64, 8 waves, 8-phase counted-vmcnt schedule
// (verified round 2). See round-2 comments for the schedule/vmcnt proof.
// ---------------------------------------------------------------------------
__device__ __forceinline__ void stage_half(const bf16* __restrict__ src, int Kd,
                                           int rbase, int k0, char* hb8,
                                           int wid, int l) {
#pragma unroll
  for (int j = 0; j < 2; ++j) {
    int Cc = wid * 128 + j * 64 + l;
    int cc = Cc ^ (((Cc >> 3) & 3) << 1);
    gl_lds16(src + (size_t)(rbase + (cc >> 3)) * Kd + k0 + (cc & 7) * 8,
             hb8 + wid * 2048 + j * 1024);
  }
}

__device__ __forceinline__ v8bf ldsfrag(const char* base, int row, int kb) {
  int p = row * 128 + kb;
  p ^= ((p >> 7) & 3) << 5;
  return *(const v8bf*)(base + p);
}

__device__ __forceinline__ void rd_a(v8bf (&af)[2][4], const char* ab, int mh, int l) {
  const int rb = mh * 64 + (l & 15);
  const int kb = (l >> 4) * 16;
#pragma unroll
  for (int ks = 0; ks < 2; ++ks)
#pragma unroll
    for (int mf = 0; mf < 4; ++mf)
      af[ks][mf] = ldsfrag(ab, rb + mf * 16, ks * 64 + kb);
}

__device__ __forceinline__ void rd_b(v8bf (&bfr)[2][2], const char* bbp, int nh, int wl, int l) {
  const int rb = wl + nh * 32 + (l & 15);
  const int kb = (l >> 4) * 16;
#pragma unroll
  for (int ks = 0; ks < 2; ++ks)
#pragma unroll
    for (int nf = 0; nf < 2; ++nf)
      bfr[ks][nf] = ldsfrag(bbp, rb + nf * 16, ks * 64 + kb);
}

__device__ __forceinline__ void qmfma(v4f (&q)[4][2], const v8bf (&af)[2][4],
                                      const v8bf (&bfr)[2][2]) {
  __builtin_amdgcn_s_setprio(1);
#pragma unroll
  for (int ks = 0; ks < 2; ++ks)
#pragma unroll
    for (int mf = 0; mf < 4; ++mf)
#pragma unroll
      for (int nf = 0; nf < 2; ++nf)
        q[mf][nf] = __builtin_amdgcn_mfma_f32_16x16x32_bf16(af[ks][mf], bfr[ks][nf],
                                                            q[mf][nf], 0, 0, 0);
  __builtin_amdgcn_s_setprio(0);
}

#define PHASE_BAR() do { __builtin_amdgcn_s_barrier(); __builtin_amdgcn_sched_barrier(0); } while (0)

template <int EPI>
__global__ __launch_bounds__(512, 2) void bgemm8(
    const bf16* __restrict__ A, const bf16* __restrict__ Wt,
    const float* __restrict__ bias, void* __restrict__ Cv, int N, int Kd) {
  __shared__ __align__(16) char smem[131072];
  const int tid = threadIdx.x;
  const int wid = tid >> 6, l = tid & 63;
  int bm, bn;
  xcd_swizzle256(bm, bn);
  const int ha = wid >> 2;            // this wave's A half
  const int hbv = (wid & 3) >> 1;     // this wave's B half
  const int wl = (wid & 1) * 64;      // B row base within half
  const int NT = Kd >> 6;             // K-tiles (BK=64), NT >= 2

  v4f acc[2][2][4][2];
  v4f z4 = {0.0f, 0.0f, 0.0f, 0.0f};
#pragma unroll
  for (int a = 0; a < 2; ++a)
#pragma unroll
    for (int b = 0; b < 2; ++b)
#pragma unroll
      for (int c = 0; c < 4; ++c)
#pragma unroll
        for (int d = 0; d < 2; ++d) acc[a][b][c][d] = z4;

  // prologue: tile0 {A0,A1,B0,B1}, tile1 {A0,A1}; keep 4 in flight (=A(1))
  stage_half(A,  Kd, bm,       0,  smem + 0,     wid, l);
  stage_half(A,  Kd, bm + 128, 0,  smem + 16384, wid, l);
  stage_half(Wt, Kd, bn,       0,  smem + 32768, wid, l);
  stage_half(Wt, Kd, bn + 128, 0,  smem + 49152, wid, l);
  stage_half(A,  Kd, bm,       64, smem + 65536, wid, l);
  stage_half(A,  Kd, bm + 128, 64, smem + 81920, wid, l);
  asm volatile("s_waitcnt vmcnt(4)" ::: "memory");
  PHASE_BAR();

  for (int K = 0; K < NT; ++K) {
    const int cur = K & 1;
    const char* ab = smem + cur * 65536 + ha * 16384;
    const char* bb = smem + cur * 65536 + 32768 + hbv * 16384;
    char* stB = smem + ((K + 1) & 1) * 65536 + 32768;
    char* stA = smem + cur * 65536;
    const int kB = (K + 1 < NT) ? (K + 1) << 6 : 0;   // clamp: dummy keeps vmcnt exact
    const int kA = (K + 2 < NT) ? (K + 2) << 6 : 0;
    v8bf a0[2][4], a1[2][4], b0[2][2], b1[2][2];

    // q0: Q(0,0) — read a0,b0; stage B-half0(K+1)
    rd_a(a0, ab, 0, l);
    rd_b(b0, bb, 0, wl, l);
    stage_half(Wt, Kd, bn, kB, stB, wid, l);
    PHASE_BAR();
    qmfma(acc[0][0], a0, b0);
    PHASE_BAR();
    // q1: Q(0,1) — read b1; stage B-half1(K+1); a0 dies here
    rd_b(b1, bb, 1, wl, l);
    stage_half(Wt, Kd, bn + 128, kB, stB + 16384, wid, l);
    PHASE_BAR();
    qmfma(acc[0][1], a0, b1);
    PHASE_BAR();
    // q2: Q(1,0) — read a1 (last A read of this tile); b0 dies here
    rd_a(a1, ab, 1, l);
    PHASE_BAR();
    qmfma(acc[1][0], a1, b0);
    PHASE_BAR();
    // q3: Q(1,1) — reg-only compute; stage A(K+2) over this tile's A region
    stage_half(A, Kd, bm, kA, stA, wid, l);
    stage_half(A, Kd, bm + 128, kA, stA + 16384, wid, l);
    PHASE_BAR();
    qmfma(acc[1][1], a1, b1);
    asm volatile("s_waitcnt vmcnt(4)" ::: "memory");
    PHASE_BAR();
  }
  asm volatile("s_waitcnt vmcnt(0)" ::: "memory");

  const int r0 = bm + ha * 128 + ((l >> 4) << 2);
  const int c0 = bn + (wid & 3) * 64 + (l & 15);
  float bb4[2][2];
  if (EPI != 0) {
#pragma unroll
    for (int nh = 0; nh < 2; ++nh)
#pragma unroll
      for (int nf = 0; nf < 2; ++nf) bb4[nh][nf] = bias[c0 + nh * 32 + nf * 16];
  }
#pragma unroll
  for (int mh = 0; mh < 2; ++mh)
#pragma unroll
    for (int mf = 0; mf < 4; ++mf)
#pragma unroll
      for (int i = 0; i < 4; ++i) {
        const int row = r0 + mh * 64 + mf * 16 + i;
#pragma unroll
        for (int nh = 0; nh < 2; ++nh)
#pragma unroll
          for (int nf = 0; nf < 2; ++nf) {
            const int col = c0 + nh * 32 + nf * 16;
            float v = acc[mh][nh][mf][nf][i];
            if (EPI == 0) {
              v = v / (1.0f + __expf(-v));
              ((bf16*)Cv)[(size_t)row * N + col] = (bf16)v;
            } else if (EPI == 1) {
              v += bb4[nh][nf];
              ((bf16*)Cv)[(size_t)row * N + col] = (bf16)v;
            } else {
              v += bb4[nh][nf];
              ((float*)Cv)[(size_t)row * N + col] = v;
            }
          }
      }
}

// ---------------------------------------------------------------------------
// row layernorm + relu, in place; block per row
// ---------------------------------------------------------------------------
template <int VPT, typename T>
__global__ __launch_bounds__(256) void ln_relu(T* __restrict__ x,
    const float* __restrict__ g, const float* __restrict__ b) {
  const int N = VPT * 256;
  const size_t base = (size_t)blockIdx.x * N;
  const int tid = threadIdx.x, w = tid >> 6, l = tid & 63;
  float v[VPT];
#pragma unroll
  for (int q = 0; q < VPT; ++q) v[q] = (float)x[base + q * 256 + tid];
  float s = 0.0f;
#pragma unroll
  for (int q = 0; q < VPT; ++q) s += v[q];
#pragma unroll
  for (int m = 1; m < 64; m <<= 1) s += __shfl_xor(s, m, 64);
  __shared__ float red[8];
  if (l == 0) red[w] = s;
  __syncthreads();
  float mean = (red[0] + red[1] + red[2] + red[3]) * (1.0f / N);
  float ss = 0.0f;
#pragma unroll
  for (int q = 0; q < VPT; ++q) { float t = v[q] - mean; ss += t * t; }
#pragma unroll
  for (int m = 1; m < 64; m <<= 1) ss += __shfl_xor(ss, m, 64);
  if (l == 0) red[4 + w] = ss;
  __syncthreads();
  float var = (red[4] + red[5] + red[6] + red[7]) * (1.0f / N);
  float rs = 1.0f / sqrtf(var + 1e-5f);
#pragma unroll
  for (int q = 0; q < VPT; ++q) {
    int j = q * 256 + tid;
    float y = (v[q] - mean) * rs * g[j] + b[j];
    x[base + j] = (T)fmaxf(y, 0.0f);
  }
}

// ---------------------------------------------------------------------------
// launch
// ---------------------------------------------------------------------------
extern "C" void kernel_launch(void* const* d_in, const int* in_sizes, int n_in,
                              void* d_out, int out_size, void* d_ws, size_t ws_size,
                              hipStream_t stream) {
  (void)in_sizes; (void)n_in; (void)out_size; (void)ws_size;
  const float* semI  = (const float*)d_in[0];
  const float* colI  = (const float*)d_in[1];
  const float* gw1   = (const float*)d_in[2];
  const float* gb1   = (const float*)d_in[3];
  const float* glng  = (const float*)d_in[4];
  const float* glnb  = (const float*)d_in[5];
  const float* gw2   = (const float*)d_in[6];
  const float* gb2   = (const float*)d_in[7];
  const float* fg    = (const float*)d_in[8];
  const float* fb    = (const float*)d_in[9];
  const float* ew1   = (const float*)d_in[10];
  const float* ew2   = (const float*)d_in[11];
  const float* ew3   = (const float*)d_in[12];
  const float* ew4   = (const float*)d_in[13];
  const float* dw1   = (const float*)d_in[14];
  const float* dw2   = (const float*)d_in[15];
  const float* dw3   = (const float*)d_in[16];
  const float* sw1   = (const float*)d_in[17];
  const float* sb1   = (const float*)d_in[18];
  const float* slng  = (const float*)d_in[19];
  const float* slnb  = (const float*)d_in[20];
  const float* sw2   = (const float*)d_in[21];
  const float* sb2   = (const float*)d_in[22];
  const float* cw1   = (const float*)d_in[23];
  const float* cb1   = (const float*)d_in[24];
  const float* clng  = (const float*)d_in[25];
  const float* clnb  = (const float*)d_in[26];
  const float* cw2   = (const float*)d_in[27];
  const float* cb2   = (const float*)d_in[28];
  const float* cbk   = (const float*)d_in[29];

  float* out = (float*)d_out;
  char* ws = (char*)d_ws;

  // output offsets (floats)
  const size_t OUT_SEM = 0, OUT_COL = 50331648, OUT_ZQ = 54525952,
               OUT_CODES = 58720256, OUT_CB = 58916864, OUT_GATE = 58916866;

  // ws layout (bytes)
  bf16* dec1t = (bf16*)(ws + 0);
  bf16* dec2t = (bf16*)(ws + 16384);
  bf16* dec3t = (bf16*)(ws + 81920);
  bf16* sem1t = (bf16*)(ws + 344064);
  bf16* sem2t = (bf16*)(ws + 1916928);
  bf16* col1t = (bf16*)(ws + 4276224);
  float* cbT  = (float*)(ws + 4538368);
  float* nhn  = (float*)(ws + 4734976);
  f16* e1w0   = (f16*)(ws + 4739072);
  f16* e1w1   = (f16*)(ws + 5591040);
  f16* e2w0   = (f16*)(ws + 6443008);
  f16* e2w1   = (f16*)(ws + 6705152);
  f16* e3w0   = (f16*)(ws + 6967296);
  f16* e3w1   = (f16*)(ws + 7032832);
  const size_t WS_A = 8388608, WS_B = 226492416;
  // fused planes occupy exactly the old fp32 fused footprint (218103808 B)
  f16* fA0 = (f16*)(ws + WS_A);
  f16* fA1 = (f16*)(ws + WS_A + 109051904);
  bf16*  semh   = (bf16*)(ws + WS_A);             // reuses plane region after E1
  float* den = (float*)(ws + WS_B);               // pre-E1 temp
  float* hn  = (float*)(ws + WS_B + 16777216);    // pre-E1 temp
  // h1/h2 planes in the old fp32 footprints
  f16* h1a = (f16*)(ws + WS_B);
  f16* h1b = (f16*)(ws + WS_B + 67108864);
  f16* h2a = (f16*)(ws + 360710144);
  f16* h2b = (f16*)(ws + 360710144 + 33554432);
  float* h3  = (float*)(ws + 427819008);
  float* rn  = (float*)(ws + 461373440);
  bf16* zqb  = (bf16*)(ws + WS_B);
  bf16* d1b  = (bf16*)(ws + WS_B + 8388608);
  bf16* d2b  = (bf16*)(ws + WS_B + 25165824);
  bf16* sb   = (bf16*)(ws + WS_B + 58720256);
  float* colh = (float*)(ws + WS_B + 125829120);

  // zero the two loss scalars (d_out is poisoned each launch)
  hipMemsetAsync(out + OUT_CB, 0, 2 * sizeof(float), stream);

  // weight prep
  wconv_t<<<(64 * 128 + 255) / 256, 256, 0, stream>>>(dw1, dec1t, 64, 128);
  wconv_t<<<(128 * 256 + 255) / 256, 256, 0, stream>>>(dw2, dec2t, 128, 256);
  wconv_t<<<(256 * 512 + 255) / 256, 256, 0, stream>>>(dw3, dec3t, 256, 512);
  wconv_t<<<(512 * 1536 + 255) / 256, 256, 0, stream>>>(sw1, sem1t, 512, 1536);
  wconv_t<<<(1536 * 768 + 255) / 256, 256, 0, stream>>>(sw2, sem2t, 1536, 768);
  wconv_t<<<(512 * 256 + 255) / 256, 256, 0, stream>>>(cw1, col1t, 512, 256);
  wsplit_t<<<(832 * 512 + 255) / 256, 256, 0, stream>>>(ew1, e1w0, e1w1, 832, 512);
  wsplit_t<<<(512 * 256 + 255) / 256, 256, 0, stream>>>(ew2, e2w0, e2w1, 512, 256);
  wsplit_t<<<(256 * 128 + 255) / 256, 256, 0, stream>>>(ew3, e3w0, e3w1, 256, 128);
  cbt_k<<<192, 256, 0, stream>>>(cbk, cbT);
  nhn_k<<<3, 256, 0, stream>>>(cbk, nhn);

  // gate network (fp32)
  sgemm128<2><<<dim3(1, 512), 256, 0, stream>>>(colI, gw1, gb1, glng, glnb, hn, 128, 64);
  sgemm64<2><<<512, 256, 0, stream>>>(hn, gw2, gb2, colI, out + OUT_GATE, den, 128);
  fuse_ln<<<4096, 256, 0, stream>>>(semI, den, fg, fb, fA0, fA1);

  // encoder: pre-split fp16 planes, m97 structure, no in-loop VALU split
  hgemmp<0><<<dim3(4, 512), 256, 0, stream>>>(fA0, fA1, e1w0, e1w1, h1a, h1b, nullptr, 512, 832);
  hgemmp<0><<<dim3(2, 512), 256, 0, stream>>>(h1a, h1b, e2w0, e2w1, h2a, h2b, nullptr, 256, 512);
  hgemmp<1><<<dim3(1, 512), 256, 0, stream>>>(h2a, h2b, e3w0, e3w1, nullptr, nullptr, h3, 128, 256);
  sgemm64<0><<<512, 256, 0, stream>>>(h3, ew4, nullptr, nullptr, rn, nullptr, 128);

  // residual quantization — single fused kernel (scores+argmax+update x3)
  rq_all<<<1024, 256, 0, stream>>>(rn, cbT, nhn, cbk,
                                   out + OUT_ZQ, out + OUT_CODES, out + OUT_CB, zqb);

  // decoder + heads (bf16 MFMA; big GEMMs on the 256^2 8-phase structure)
  bgemm<0><<<dim3(1, 512), 256, 0, stream>>>(zqb, dec1t, nullptr, d1b, 128, 64);
  bgemm8<0><<<dim3(1, 256), 512, 0, stream>>>(d1b, dec2t, nullptr, d2b, 256, 128);
  bgemm8<0><<<dim3(2, 256), 512, 0, stream>>>(d2b, dec3t, nullptr, sb, 512, 256);
  bgemm8<1><<<dim3(6, 256), 512, 0, stream>>>(sb, sem1t, sb1, semh, 1536, 512);
  ln_relu<6, bf16><<<65536, 256, 0, stream>>>(semh, slng, slnb);
  bgemm8<2><<<dim3(3, 256), 512, 0, stream>>>(semh, sem2t, sb2, out + OUT_SEM, 768, 1536);
  bgemm8<2><<<dim3(1, 256), 512, 0, stream>>>(sb, col1t, cb1, colh, 256, 512);
  ln_relu<1, float><<<65536, 256, 0, stream>>>(colh, clng, clnb);
  sgemm64<1><<<512, 256, 0, stream>>>(colh, cw2, cb2, nullptr, out + OUT_COL, nullptr, 256);
}